// Round 13
// baseline (425.383 us; speedup 1.0000x reference)
//
#include <hip/hip_runtime.h>
#include <cstddef>
#include <cstdint>

typedef _Float16 half8 __attribute__((ext_vector_type(8)));
typedef float f32x4 __attribute__((ext_vector_type(4)));
typedef float f32x2 __attribute__((ext_vector_type(2)));
typedef unsigned short ushort_t;
typedef unsigned int uint_t;
typedef ushort_t ushort4v __attribute__((ext_vector_type(4)));
typedef float f32x4v __attribute__((ext_vector_type(4)));

#define INV_LN2 1.4426950408889634f
#define RESCALE_THR 12.0f

__device__ __forceinline__ float bf16_to_f(ushort_t u) {
  union { unsigned int i; float f; } v; v.i = ((unsigned int)u) << 16; return v.f;
}
__device__ __forceinline__ float lo16f(uint_t u) {
  union { uint_t i; float f; } v; v.i = u << 16; return v.f;
}
__device__ __forceinline__ float hi16f(uint_t u) {
  union { uint_t i; float f; } v; v.i = u & 0xffff0000u; return v.f;
}
__device__ __forceinline__ ushort_t f_to_bf16(float f) {
  union { float ff; unsigned int i; } v; v.ff = f;
  unsigned int x = v.i;
  unsigned int lsb = (x >> 16) & 1u;
  x += 0x7fffu + lsb;
  return (ushort_t)(x >> 16);
}
__device__ __forceinline__ uint_t pack_hl(float f) {
  ushort_t hb = f_to_bf16(f);
  ushort_t lb = f_to_bf16(f - bf16_to_f(hb));
  return (uint_t)hb | ((uint_t)lb << 16);
}
__device__ __forceinline__ ushort_t f_to_f16(float f) {
  _Float16 h = (_Float16)f;
  union { _Float16 h; ushort_t u; } v; v.h = h; return v.u;
}
__device__ __forceinline__ float f16_to_f(ushort_t u) {
  union { ushort_t u; _Float16 h; } v; v.u = u; return (float)v.h;
}

// ---------------------------------------------------------------------------
// CSR build
// ---------------------------------------------------------------------------
__global__ __launch_bounds__(64) void detect_i64_kernel(const int* __restrict__ ei,
                                                        int* __restrict__ flag) {
  if (threadIdx.x == 0) {
    int is32 = 0;
    for (int i = 1; i < 1001; i += 2) {
      if (ei[i] != 0) { is32 = 1; break; }
    }
    *flag = is32;
  }
}

__device__ __forceinline__ int load_src(const int* ei, int is32, int E, int e) {
  return is32 ? ei[e] : ei[2 * e];
}
__device__ __forceinline__ int load_dst(const int* ei, int is32, int E, int e) {
  return is32 ? ei[E + e] : ei[2 * (E + e)];
}

__global__ __launch_bounds__(256) void deg_kernel(const int* __restrict__ ei,
                                                  const int* __restrict__ flag,
                                                  int E, int N, int* __restrict__ deg) {
  int e = blockIdx.x * 256 + threadIdx.x;
  if (e >= E + N) return;
  int d = (e < E) ? load_dst(ei, *flag, E, e) : (e - E);
  atomicAdd(&deg[d], 1);
}

__global__ __launch_bounds__(256) void scan_blk_kernel(const int* __restrict__ deg,
                                                       int* __restrict__ rowptr,
                                                       int* __restrict__ bsum, int N) {
  __shared__ int buf[256];
  int b = blockIdx.x, t = threadIdx.x, i = b * 256 + t;
  int v = (i < N) ? deg[i] : 0;
  buf[t] = v;
  __syncthreads();
  for (int off = 1; off < 256; off <<= 1) {
    int add = (t >= off) ? buf[t - off] : 0;
    __syncthreads();
    buf[t] += add;
    __syncthreads();
  }
  if (i < N) rowptr[i + 1] = buf[t];
  if (t == 255) bsum[b] = buf[255];
  if (b == 0 && t == 0) rowptr[0] = 0;
}

__global__ __launch_bounds__(256) void scan_top_kernel(int* __restrict__ bsum, int NB) {
  __shared__ int buf[256];
  int t = threadIdx.x;
  int v = (t < NB) ? bsum[t] : 0;
  buf[t] = v;
  __syncthreads();
  for (int off = 1; off < 256; off <<= 1) {
    int add = (t >= off) ? buf[t - off] : 0;
    __syncthreads();
    buf[t] += add;
    __syncthreads();
  }
  if (t < NB) bsum[t] = buf[t];
}

__global__ __launch_bounds__(256) void scan_add_kernel(int* __restrict__ rowptr,
                                                       const int* __restrict__ bsum, int N) {
  int b = blockIdx.x, t = threadIdx.x, i = b * 256 + t;
  if (b > 0 && i < N) rowptr[i + 1] += bsum[b - 1];
}

__global__ __launch_bounds__(256) void fill_kernel(const int* __restrict__ ei,
                                                   const int* __restrict__ flag,
                                                   int E, int N,
                                                   const int* __restrict__ rowptr,
                                                   int* __restrict__ fillc,
                                                   int* __restrict__ colbuf) {
  int e = blockIdx.x * 256 + threadIdx.x;
  if (e >= E + N) return;
  int s, d;
  if (e < E) { int is32 = *flag; s = load_src(ei, is32, E, e); d = load_dst(ei, is32, E, e); }
  else { s = e - E; d = s; }
  int pos = atomicAdd(&fillc[d], 1);
  colbuf[rowptr[d] + pos] = s;
}

// ---------------------------------------------------------------------------
// prep kernels
// ---------------------------------------------------------------------------
// fp32 -> packed (bf16hi|bf16lo) uint (for al) + fp16 ushort (for agg gather)
__global__ __launch_bounds__(256) void split_x_i_kernel(const float* __restrict__ h,
                                                        uint_t* __restrict__ hi,
                                                        ushort_t* __restrict__ h16,
                                                        int n) {
  int i = (blockIdx.x * 256 + threadIdx.x) * 4;
  if (i >= n) return;
  f32x4v v = *(const f32x4v*)&h[i];
  uint4 o;
  o.x = pack_hl(v[0]); o.y = pack_hl(v[1]); o.z = pack_hl(v[2]); o.w = pack_hl(v[3]);
  *(uint4*)&hi[i] = o;
  ushort4v s;
  s[0] = f_to_f16(v[0]); s[1] = f_to_f16(v[1]);
  s[2] = f_to_f16(v[2]); s[3] = f_to_f16(v[3]);
  *(ushort4v*)&h16[i] = s;
}

// Wp [k=128][col=128] fp32 -> fp16 frag layout
__global__ __launch_bounds__(256) void split_wt_frag_kernel(const float* __restrict__ W,
                                                            ushort_t* __restrict__ Wf) {
  int t = blockIdx.x * 256 + threadIdx.x;   // 16384
  int blk = t >> 7, rem = t & 127;
  int c16 = blk >> 4, k8 = blk & 15;
  int cl = rem >> 3, kl = rem & 7;
  int col = c16 * 16 + cl, k = k8 * 8 + kl;
  Wf[t] = f_to_f16(W[(size_t)k * 128 + col]);
}

// W [128][512] -> Wstack fp16 frag layout (K=512), val = 0.25*W[f][h*128+col]
__global__ __launch_bounds__(256) void split_wstack_frag_kernel(const float* __restrict__ W,
                                                                ushort_t* __restrict__ Wf) {
  int t = blockIdx.x * 256 + threadIdx.x;   // 65536
  int c16 = t >> 13;
  int r = t & 8191;
  int k8 = r >> 7;
  int rem = r & 127;
  int rl = rem >> 3, kl = rem & 7;
  int col = c16 * 16 + rl;
  int k = k8 * 8 + kl;
  int h = k >> 7, f = k & 127;
  Wf[t] = f_to_f16(0.25f * W[(size_t)f * 512 + h * 128 + col]);
}

// Ws[h*128+f] = (1/ln2) * sum_d W[f, h*128+d] * a_src[h, d]
__global__ __launch_bounds__(256) void wsd_kernel(const float* __restrict__ W,
                                                  const float* __restrict__ a_src,
                                                  const float* __restrict__ a_dst,
                                                  float* __restrict__ Ws,
                                                  float* __restrict__ Wd) {
  int wave = threadIdx.x >> 6, lane = threadIdx.x & 63;
  int f = blockIdx.x * 4 + wave;          // grid = 32 -> f in [0,128)
  int base = lane * 8;
  float4 w0 = *(const float4*)&W[(size_t)f * 512 + base];
  float4 w1 = *(const float4*)&W[(size_t)f * 512 + base + 4];
  float4 s0 = *(const float4*)&a_src[base];
  float4 s1 = *(const float4*)&a_src[base + 4];
  float4 d0 = *(const float4*)&a_dst[base];
  float4 d1 = *(const float4*)&a_dst[base + 4];
  float ps = w0.x*s0.x + w0.y*s0.y + w0.z*s0.z + w0.w*s0.w
           + w1.x*s1.x + w1.y*s1.y + w1.z*s1.z + w1.w*s1.w;
  float pd = w0.x*d0.x + w0.y*d0.y + w0.z*d0.z + w0.w*d0.w
           + w1.x*d1.x + w1.y*d1.y + w1.z*d1.z + w1.w*d1.w;
#pragma unroll
  for (int off = 1; off <= 8; off <<= 1) {
    ps += __shfl_xor(ps, off);
    pd += __shfl_xor(pd, off);
  }
  if ((lane & 15) == 0) {
    int h = lane >> 4;
    Ws[h * 128 + f] = ps * INV_LN2;
    Wd[h * 128 + f] = pd * INV_LN2;
  }
}

// al_src/al_dst [N,4] from packed hi/lo h (full precision). One wave per node.
__global__ __launch_bounds__(256) void al_kernel_i(const uint_t* __restrict__ hint,
                                                   const float* __restrict__ Ws,
                                                   const float* __restrict__ Wd,
                                                   float* __restrict__ al_src,
                                                   float* __restrict__ al_dst, int N) {
  __shared__ float sWs[512], sWd[512];
  int t = threadIdx.x;
  sWs[t] = Ws[t]; sWs[t + 256] = Ws[t + 256];
  sWd[t] = Wd[t]; sWd[t + 256] = Wd[t + 256];
  __syncthreads();
  int wave = t >> 6, lane = t & 63;
  int n = blockIdx.x * 4 + wave;
  if (n >= N) return;
  uint2 uu = *(const uint2*)&hint[(size_t)n * 128 + lane * 2];
  float v0 = lo16f(uu.x) + hi16f(uu.x);
  float v1 = lo16f(uu.y) + hi16f(uu.y);
  float p[8];
#pragma unroll
  for (int hh = 0; hh < 4; ++hh) {
    p[hh]     = v0 * sWs[hh * 128 + 2 * lane] + v1 * sWs[hh * 128 + 2 * lane + 1];
    p[4 + hh] = v0 * sWd[hh * 128 + 2 * lane] + v1 * sWd[hh * 128 + 2 * lane + 1];
  }
#pragma unroll
  for (int off = 32; off; off >>= 1)
#pragma unroll
    for (int i = 0; i < 8; ++i) p[i] += __shfl_xor(p[i], off);
  if (lane == 0) {
#pragma unroll
    for (int hh = 0; hh < 4; ++hh) {
      al_src[n * 4 + hh] = p[hh];
      al_dst[n * 4 + hh] = p[4 + hh];
    }
  }
}

// ---------------------------------------------------------------------------
// aggregation: 2 nodes per wave (32-lane halves); fp16 value gather (8 B/lane);
// exp2-domain online softmax, deferred rescale; 2-deep pipelined gathers;
// packed dual-f32 (v_pk_*) arithmetic via float2 vectors; fp16 frag output.
// ---------------------------------------------------------------------------
__global__ __launch_bounds__(256) void agg_G_kernel(const ushort_t* __restrict__ h16,
                                                    const float* __restrict__ al_src,
                                                    const float* __restrict__ al_dst,
                                                    const int* __restrict__ rowptr,
                                                    const int* __restrict__ colbuf,
                                                    ushort_t* __restrict__ Gf, int N) {
  int wave = threadIdx.x >> 6, lane = threadIdx.x & 63;
  int fl = lane & 31;
  int n = blockIdx.x * 8 + wave * 2 + (lane >> 5);
  bool alive = n < N;
  int beg = 0, d = 0;
  float4 aldf = make_float4(0.f, 0.f, 0.f, 0.f);
  if (alive) {
    beg = rowptr[n];
    d = rowptr[n + 1] - beg;
    aldf = *(const float4*)&al_dst[(size_t)n * 4];
  }
  f32x2 ald01 = {aldf.x, aldf.y}, ald23 = {aldf.z, aldf.w};
  int dmax = max(d, __shfl_xor(d, 32));
  int dm1 = max(d - 1, 0);
  f32x2 m01 = {-1e30f, -1e30f}, m23 = {-1e30f, -1e30f};
  f32x2 t01 = {-1e30f, -1e30f}, t23 = {-1e30f, -1e30f};
  f32x2 ss01 = {0.f, 0.f}, ss23 = {0.f, 0.f};
  f32x2 acc0a = {0.f, 0.f}, acc0b = {0.f, 0.f};
  f32x2 acc1a = {0.f, 0.f}, acc1b = {0.f, 0.f};
  f32x2 acc2a = {0.f, 0.f}, acc2b = {0.f, 0.f};
  f32x2 acc3a = {0.f, 0.f}, acc3b = {0.f, 0.f};

  if (dmax > 0) {
    int s0i = colbuf[beg];
    float4 as_c = *(const float4*)&al_src[(size_t)s0i * 4];
    ushort4v hv_c = *(const ushort4v*)&h16[(size_t)s0i * 128 + fl * 4];
    int s_n = colbuf[beg + min(1, dm1)];
    for (int it = 0; it < dmax; ++it) {
      float4 as_n = *(const float4*)&al_src[(size_t)s_n * 4];
      ushort4v hv_n = *(const ushort4v*)&h16[(size_t)s_n * 128 + fl * 4];
      int s_n2 = colbuf[beg + min(it + 2, dm1)];

      f32x2 e01 = f32x2{as_c.x, as_c.y} + ald01;
      f32x2 e23 = f32x2{as_c.z, as_c.w} + ald23;
      e01 = __builtin_elementwise_max(e01, 0.2f * e01);   // leaky relu, packed
      e23 = __builtin_elementwise_max(e23, 0.2f * e23);
      bool need = (e01.x > t01.x) || (e01.y > t01.y) ||
                  (e23.x > t23.x) || (e23.y > t23.y);
      if (__any(need)) {
        f32x2 nm01 = __builtin_elementwise_max(m01, e01);
        f32x2 nm23 = __builtin_elementwise_max(m23, e23);
        f32x2 d01v = m01 - nm01, d23v = m23 - nm23;
        f32x2 f01 = {exp2f(d01v.x), exp2f(d01v.y)};
        f32x2 f23 = {exp2f(d23v.x), exp2f(d23v.y)};
        m01 = nm01; m23 = nm23;
        t01 = nm01 + RESCALE_THR; t23 = nm23 + RESCALE_THR;
        ss01 *= f01; ss23 *= f23;
        f32x2 f0 = {f01.x, f01.x}, f1 = {f01.y, f01.y};
        f32x2 f2 = {f23.x, f23.x}, f3 = {f23.y, f23.y};
        acc0a *= f0; acc0b *= f0;
        acc1a *= f1; acc1b *= f1;
        acc2a *= f2; acc2b *= f2;
        acc3a *= f3; acc3b *= f3;
      }
      f32x2 d01v = e01 - m01, d23v = e23 - m23;
      f32x2 w01 = {exp2f(d01v.x), exp2f(d01v.y)};
      f32x2 w23 = {exp2f(d23v.x), exp2f(d23v.y)};
      bool valid = it < d;
      w01 = valid ? w01 : f32x2{0.f, 0.f};
      w23 = valid ? w23 : f32x2{0.f, 0.f};
      ss01 += w01; ss23 += w23;
      f32x2 v01 = {f16_to_f(hv_c[0]), f16_to_f(hv_c[1])};
      f32x2 v23 = {f16_to_f(hv_c[2]), f16_to_f(hv_c[3])};
      f32x2 w0s = {w01.x, w01.x}, w1s = {w01.y, w01.y};
      f32x2 w2s = {w23.x, w23.x}, w3s = {w23.y, w23.y};
      acc0a += w0s * v01; acc0b += w0s * v23;
      acc1a += w1s * v01; acc1b += w1s * v23;
      acc2a += w2s * v01; acc2b += w2s * v23;
      acc3a += w3s * v01; acc3b += w3s * v23;
      as_c = as_n; hv_c = hv_n; s_n = s_n2;
    }
  }
  if (!alive) return;
  float g[4][4];
  float inv;
  inv = 1.f / (ss01.x + 1e-16f);
  g[0][0] = acc0a.x * inv; g[0][1] = acc0a.y * inv; g[0][2] = acc0b.x * inv; g[0][3] = acc0b.y * inv;
  inv = 1.f / (ss01.y + 1e-16f);
  g[1][0] = acc1a.x * inv; g[1][1] = acc1a.y * inv; g[1][2] = acc1b.x * inv; g[1][3] = acc1b.y * inv;
  inv = 1.f / (ss23.x + 1e-16f);
  g[2][0] = acc2a.x * inv; g[2][1] = acc2a.y * inv; g[2][2] = acc2b.x * inv; g[2][3] = acc2b.y * inv;
  inv = 1.f / (ss23.y + 1e-16f);
  g[3][0] = acc3a.x * inv; g[3][1] = acc3a.y * inv; g[3][2] = acc3b.x * inv; g[3][3] = acc3b.y * inv;
#pragma unroll
  for (int h = 0; h < 4; ++h) {
    ushort_t q0 = f_to_f16(g[h][0]), q1 = f_to_f16(g[h][1]);
    ushort_t q2 = f_to_f16(g[h][2]), q3 = f_to_f16(g[h][3]);
    size_t o = ((size_t)(n >> 4) * 64 + h * 16 + (fl >> 1)) * 128 + (n & 15) * 8 + (fl & 1) * 4;
    *(uint2*)&Gf[o] = make_uint2((uint_t)q0 | ((uint_t)q1 << 16),
                                 (uint_t)q2 | ((uint_t)q3 << 16));
  }
}

// ---------------------------------------------------------------------------
// Barrier-free fp16 MFMA GEMM from fragment-layout inputs. Compile-time K/MODE.
// 4 waves/block, 16 rows/wave, single MFMA pass (fp32 accumulate).
// MODE 0: packed-uint + fp16 row out (relu); 1: fp16 frag out (relu);
// MODE 2: fp32 row out (no relu).
// ---------------------------------------------------------------------------
template <int K, int MODE>
__global__ __launch_bounds__(256) void gemm_frag_kernel(
    const ushort_t* __restrict__ Af, const ushort_t* __restrict__ Bf,
    uint_t* __restrict__ Ci, ushort_t* __restrict__ H16,
    ushort_t* __restrict__ Cf16, float* __restrict__ Cf,
    int M, const float* __restrict__ bias) {
  constexpr int KT = K >> 5;
  constexpr int PS = 16 * K;          // panel stride (ushorts)
  int lane = threadIdx.x & 63;
  int wid = blockIdx.x * 4 + (threadIdx.x >> 6);
  int krow = lane >> 4, ml = lane & 15;
  int lb = krow * 128 + ml * 8;
  size_t abase = (size_t)wid * PS + lb;
  f32x4 acc[8] = {};
  half8 a_c = *(const half8*)&Af[abase];
#pragma unroll
  for (int kt = 0; kt < KT; ++kt) {
    half8 a_n = a_c;
    if (kt + 1 < KT) a_n = *(const half8*)&Af[abase + (kt + 1) * 512];
    half8 b[8];
#pragma unroll
    for (int j = 0; j < 8; ++j)
      b[j] = *(const half8*)&Bf[j * PS + kt * 512 + lb];
#pragma unroll
    for (int j = 0; j < 8; ++j)
      acc[j] = __builtin_amdgcn_mfma_f32_16x16x32_f16(a_c, b[j], acc[j], 0, 0, 0);
    a_c = a_n;
  }
  int wrow0 = wid * 16;
#pragma unroll
  for (int j = 0; j < 8; ++j) {
    int col = j * 16 + ml;
    float bv = bias[col];
#pragma unroll
    for (int r = 0; r < 4; ++r) {
      int row = wrow0 + krow * 4 + r;
      if (row < M) {
        float v = acc[j][r] + bv;
        if (MODE != 2) v = fmaxf(v, 0.f);
        if (MODE == 0) {
          Ci[(size_t)row * 128 + col] = pack_hl(v);
          H16[(size_t)row * 128 + col] = f_to_f16(v);
        } else if (MODE == 1) {
          size_t o = ((size_t)(row >> 4) * 16 + (col >> 3)) * 128 + (row & 15) * 8 + (col & 7);
          Cf16[o] = f_to_f16(v);
        } else {
          Cf[(size_t)row * 128 + col] = v;
        }
      }
    }
  }
}

// ---------------------------------------------------------------------------
extern "C" void kernel_launch(void* const* d_in, const int* in_sizes, int n_in,
                              void* d_out, int out_size, void* d_ws, size_t ws_size,
                              hipStream_t stream) {
  const float* x  = (const float*)d_in[0];
  const int*   ei = (const int*)d_in[1];
  const float* Wl[3]  = {(const float*)d_in[2], (const float*)d_in[6], (const float*)d_in[10]};
  const float* asr[3] = {(const float*)d_in[3], (const float*)d_in[7], (const float*)d_in[11]};
  const float* adr[3] = {(const float*)d_in[4], (const float*)d_in[8], (const float*)d_in[12]};
  const float* bl[3]  = {(const float*)d_in[5], (const float*)d_in[9], (const float*)d_in[13]};
  const float* Wp = (const float*)d_in[14];
  const float* bp = (const float*)d_in[15];

  const int N = in_sizes[0] / 128;   // 50000
  const int E = in_sizes[1] / 2;     // 400000
  const int EN = E + N;
  const int Mtiles = (N + 127) / 128;  // 391
  const int Mp = Mtiles * 128;         // 50048
  const int NB = (N + 255) / 256;
  const int NPB = Mp / 16 / 4;         // 782 GEMM blocks

  char* ws = (char*)d_ws;
  size_t off = 0;
  auto carve = [&](size_t bytes) -> void* {
    void* p = ws + off;
    off = (off + bytes + 255) & ~(size_t)255;
    return p;
  };
  ushort_t* Gf    = (ushort_t*)carve((size_t)Mp * 512 * 2);  // fp16 frag layout
  uint_t*   hiA   = (uint_t*)carve((size_t)N * 128 * 4);     // packed hi/lo (al)
  uint_t*   hiB   = (uint_t*)carve((size_t)N * 128 * 4);
  ushort_t* h16   = (ushort_t*)carve((size_t)N * 128 * 2);   // fp16 (agg gather)
  ushort_t* h3f   = (ushort_t*)carve((size_t)Mp * 128 * 2);  // fp16 frag (proj input)
  ushort_t* wsf   = (ushort_t*)carve((size_t)128 * 512 * 2); // fp16 frag Wstack / Wp
  float*    alsrc = (float*)carve((size_t)N * 4 * 4);
  float*    aldst = (float*)carve((size_t)N * 4 * 4);
  float*    Wsb   = (float*)carve(512 * 4);
  float*    Wdb   = (float*)carve(512 * 4);
  int*      rowptr= (int*)carve((size_t)(N + 1) * 4);
  int*      deg   = (int*)carve((size_t)N * 4);
  int*      bsum  = (int*)carve(256 * 4);
  int*      fillc = (int*)carve((size_t)N * 4);
  int*      colbuf= (int*)carve((size_t)EN * 4);
  int*      flag  = (int*)carve(256);

  // ---- CSR build ----
  detect_i64_kernel<<<1, 64, 0, stream>>>(ei, flag);
  hipMemsetAsync(deg, 0, (size_t)N * 4, stream);
  hipMemsetAsync(fillc, 0, (size_t)N * 4, stream);
  int ebl = (EN + 255) / 256;
  deg_kernel<<<ebl, 256, 0, stream>>>(ei, flag, E, N, deg);
  scan_blk_kernel<<<NB, 256, 0, stream>>>(deg, rowptr, bsum, N);
  scan_top_kernel<<<1, 256, 0, stream>>>(bsum, NB);
  scan_add_kernel<<<NB, 256, 0, stream>>>(rowptr, bsum, N);
  fill_kernel<<<ebl, 256, 0, stream>>>(ei, flag, E, N, rowptr, fillc, colbuf);

  // ---- split x into packed + fp16 ----
  const int n_real = N * 128;
  split_x_i_kernel<<<(n_real / 4 + 255) / 256, 256, 0, stream>>>(x, hiA, h16, n_real);

  // ---- 3 GAT layers ----
  uint_t* hin = hiA;
  uint_t* hnext = hiB;
  for (int L = 0; L < 3; ++L) {
    wsd_kernel<<<32, 256, 0, stream>>>(Wl[L], asr[L], adr[L], Wsb, Wdb);
    al_kernel_i<<<(N + 3) / 4, 256, 0, stream>>>(hin, Wsb, Wdb, alsrc, aldst, N);
    agg_G_kernel<<<Mp / 8, 256, 0, stream>>>(h16, alsrc, aldst,
                                             rowptr, colbuf, Gf, N);
    split_wstack_frag_kernel<<<256, 256, 0, stream>>>(Wl[L], wsf);
    if (L < 2) {
      gemm_frag_kernel<512, 0><<<NPB, 256, 0, stream>>>(Gf, wsf,
                                                        hnext, h16, nullptr, nullptr,
                                                        N, bl[L]);
      uint_t* t = hin; hin = hnext; hnext = t;
    } else {
      gemm_frag_kernel<512, 1><<<NPB, 256, 0, stream>>>(Gf, wsf,
                                                        nullptr, nullptr, h3f, nullptr,
                                                        N, bl[L]);
    }
  }

  // ---- final projection: out = h3 @ Wp + bp ----
  split_wt_frag_kernel<<<64, 256, 0, stream>>>(Wp, wsf);
  gemm_frag_kernel<128, 2><<<NPB, 256, 0, stream>>>(h3f, wsf,
                                                    nullptr, nullptr, nullptr, (float*)d_out,
                                                    N, bp);
}

// Round 14
// 401.409 us; speedup vs baseline: 1.0597x; 1.0597x over previous
//
#include <hip/hip_runtime.h>
#include <cstddef>
#include <cstdint>

typedef _Float16 half8 __attribute__((ext_vector_type(8)));
typedef float f32x4 __attribute__((ext_vector_type(4)));
typedef float f32x2 __attribute__((ext_vector_type(2)));
typedef unsigned short ushort_t;
typedef unsigned int uint_t;
typedef ushort_t ushort4v __attribute__((ext_vector_type(4)));
typedef float f32x4v __attribute__((ext_vector_type(4)));

#define INV_LN2 1.4426950408889634f

__device__ __forceinline__ float bf16_to_f(ushort_t u) {
  union { unsigned int i; float f; } v; v.i = ((unsigned int)u) << 16; return v.f;
}
__device__ __forceinline__ float lo16f(uint_t u) {
  union { uint_t i; float f; } v; v.i = u << 16; return v.f;
}
__device__ __forceinline__ float hi16f(uint_t u) {
  union { uint_t i; float f; } v; v.i = u & 0xffff0000u; return v.f;
}
__device__ __forceinline__ ushort_t f_to_bf16(float f) {
  union { float ff; unsigned int i; } v; v.ff = f;
  unsigned int x = v.i;
  unsigned int lsb = (x >> 16) & 1u;
  x += 0x7fffu + lsb;
  return (ushort_t)(x >> 16);
}
__device__ __forceinline__ uint_t pack_hl(float f) {
  ushort_t hb = f_to_bf16(f);
  ushort_t lb = f_to_bf16(f - bf16_to_f(hb));
  return (uint_t)hb | ((uint_t)lb << 16);
}
__device__ __forceinline__ ushort_t f_to_f16(float f) {
  _Float16 h = (_Float16)f;
  union { _Float16 h; ushort_t u; } v; v.h = h; return v.u;
}
__device__ __forceinline__ float f16_to_f(ushort_t u) {
  union { ushort_t u; _Float16 h; } v; v.u = u; return (float)v.h;
}

// ---------------------------------------------------------------------------
// CSR build
// ---------------------------------------------------------------------------
__global__ __launch_bounds__(64) void detect_i64_kernel(const int* __restrict__ ei,
                                                        int* __restrict__ flag) {
  if (threadIdx.x == 0) {
    int is32 = 0;
    for (int i = 1; i < 1001; i += 2) {
      if (ei[i] != 0) { is32 = 1; break; }
    }
    *flag = is32;
  }
}

__device__ __forceinline__ int load_src(const int* ei, int is32, int E, int e) {
  return is32 ? ei[e] : ei[2 * e];
}
__device__ __forceinline__ int load_dst(const int* ei, int is32, int E, int e) {
  return is32 ? ei[E + e] : ei[2 * (E + e)];
}

__global__ __launch_bounds__(256) void deg_kernel(const int* __restrict__ ei,
                                                  const int* __restrict__ flag,
                                                  int E, int N, int* __restrict__ deg) {
  int e = blockIdx.x * 256 + threadIdx.x;
  if (e >= E + N) return;
  int d = (e < E) ? load_dst(ei, *flag, E, e) : (e - E);
  atomicAdd(&deg[d], 1);
}

__global__ __launch_bounds__(256) void scan_blk_kernel(const int* __restrict__ deg,
                                                       int* __restrict__ rowptr,
                                                       int* __restrict__ bsum, int N) {
  __shared__ int buf[256];
  int b = blockIdx.x, t = threadIdx.x, i = b * 256 + t;
  int v = (i < N) ? deg[i] : 0;
  buf[t] = v;
  __syncthreads();
  for (int off = 1; off < 256; off <<= 1) {
    int add = (t >= off) ? buf[t - off] : 0;
    __syncthreads();
    buf[t] += add;
    __syncthreads();
  }
  if (i < N) rowptr[i + 1] = buf[t];
  if (t == 255) bsum[b] = buf[255];
  if (b == 0 && t == 0) rowptr[0] = 0;
}

__global__ __launch_bounds__(256) void scan_top_kernel(int* __restrict__ bsum, int NB) {
  __shared__ int buf[256];
  int t = threadIdx.x;
  int v = (t < NB) ? bsum[t] : 0;
  buf[t] = v;
  __syncthreads();
  for (int off = 1; off < 256; off <<= 1) {
    int add = (t >= off) ? buf[t - off] : 0;
    __syncthreads();
    buf[t] += add;
    __syncthreads();
  }
  if (t < NB) bsum[t] = buf[t];
}

__global__ __launch_bounds__(256) void scan_add_kernel(int* __restrict__ rowptr,
                                                       const int* __restrict__ bsum, int N) {
  int b = blockIdx.x, t = threadIdx.x, i = b * 256 + t;
  if (b > 0 && i < N) rowptr[i + 1] += bsum[b - 1];
}

__global__ __launch_bounds__(256) void fill_kernel(const int* __restrict__ ei,
                                                   const int* __restrict__ flag,
                                                   int E, int N,
                                                   const int* __restrict__ rowptr,
                                                   int* __restrict__ fillc,
                                                   int* __restrict__ colbuf) {
  int e = blockIdx.x * 256 + threadIdx.x;
  if (e >= E + N) return;
  int s, d;
  if (e < E) { int is32 = *flag; s = load_src(ei, is32, E, e); d = load_dst(ei, is32, E, e); }
  else { s = e - E; d = s; }
  int pos = atomicAdd(&fillc[d], 1);
  colbuf[rowptr[d] + pos] = s;
}

// ---------------------------------------------------------------------------
// prep kernels
// ---------------------------------------------------------------------------
// fp32 -> packed (bf16hi|bf16lo) uint (for al) + fp16 ushort (for agg gather)
__global__ __launch_bounds__(256) void split_x_i_kernel(const float* __restrict__ h,
                                                        uint_t* __restrict__ hi,
                                                        ushort_t* __restrict__ h16,
                                                        int n) {
  int i = (blockIdx.x * 256 + threadIdx.x) * 4;
  if (i >= n) return;
  f32x4v v = *(const f32x4v*)&h[i];
  uint4 o;
  o.x = pack_hl(v[0]); o.y = pack_hl(v[1]); o.z = pack_hl(v[2]); o.w = pack_hl(v[3]);
  *(uint4*)&hi[i] = o;
  ushort4v s;
  s[0] = f_to_f16(v[0]); s[1] = f_to_f16(v[1]);
  s[2] = f_to_f16(v[2]); s[3] = f_to_f16(v[3]);
  *(ushort4v*)&h16[i] = s;
}

// Wp [k=128][col=128] fp32 -> fp16 frag layout
__global__ __launch_bounds__(256) void split_wt_frag_kernel(const float* __restrict__ W,
                                                            ushort_t* __restrict__ Wf) {
  int t = blockIdx.x * 256 + threadIdx.x;   // 16384
  int blk = t >> 7, rem = t & 127;
  int c16 = blk >> 4, k8 = blk & 15;
  int cl = rem >> 3, kl = rem & 7;
  int col = c16 * 16 + cl, k = k8 * 8 + kl;
  Wf[t] = f_to_f16(W[(size_t)k * 128 + col]);
}

// W [128][512] -> Wstack fp16 frag layout (K=512), val = 0.25*W[f][h*128+col]
__global__ __launch_bounds__(256) void split_wstack_frag_kernel(const float* __restrict__ W,
                                                                ushort_t* __restrict__ Wf) {
  int t = blockIdx.x * 256 + threadIdx.x;   // 65536
  int c16 = t >> 13;
  int r = t & 8191;
  int k8 = r >> 7;
  int rem = r & 127;
  int rl = rem >> 3, kl = rem & 7;
  int col = c16 * 16 + rl;
  int k = k8 * 8 + kl;
  int h = k >> 7, f = k & 127;
  Wf[t] = f_to_f16(0.25f * W[(size_t)f * 512 + h * 128 + col]);
}

// Ws[h*128+f] = (1/ln2) * sum_d W[f, h*128+d] * a_src[h, d]
__global__ __launch_bounds__(256) void wsd_kernel(const float* __restrict__ W,
                                                  const float* __restrict__ a_src,
                                                  const float* __restrict__ a_dst,
                                                  float* __restrict__ Ws,
                                                  float* __restrict__ Wd) {
  int wave = threadIdx.x >> 6, lane = threadIdx.x & 63;
  int f = blockIdx.x * 4 + wave;          // grid = 32 -> f in [0,128)
  int base = lane * 8;
  float4 w0 = *(const float4*)&W[(size_t)f * 512 + base];
  float4 w1 = *(const float4*)&W[(size_t)f * 512 + base + 4];
  float4 s0 = *(const float4*)&a_src[base];
  float4 s1 = *(const float4*)&a_src[base + 4];
  float4 d0 = *(const float4*)&a_dst[base];
  float4 d1 = *(const float4*)&a_dst[base + 4];
  float ps = w0.x*s0.x + w0.y*s0.y + w0.z*s0.z + w0.w*s0.w
           + w1.x*s1.x + w1.y*s1.y + w1.z*s1.z + w1.w*s1.w;
  float pd = w0.x*d0.x + w0.y*d0.y + w0.z*d0.z + w0.w*d0.w
           + w1.x*d1.x + w1.y*d1.y + w1.z*d1.z + w1.w*d1.w;
#pragma unroll
  for (int off = 1; off <= 8; off <<= 1) {
    ps += __shfl_xor(ps, off);
    pd += __shfl_xor(pd, off);
  }
  if ((lane & 15) == 0) {
    int h = lane >> 4;
    Ws[h * 128 + f] = ps * INV_LN2;
    Wd[h * 128 + f] = pd * INV_LN2;
  }
}

// al_src/al_dst [N,4] from packed hi/lo h (full precision). One wave per node.
__global__ __launch_bounds__(256) void al_kernel_i(const uint_t* __restrict__ hint,
                                                   const float* __restrict__ Ws,
                                                   const float* __restrict__ Wd,
                                                   float* __restrict__ al_src,
                                                   float* __restrict__ al_dst, int N) {
  __shared__ float sWs[512], sWd[512];
  int t = threadIdx.x;
  sWs[t] = Ws[t]; sWs[t + 256] = Ws[t + 256];
  sWd[t] = Wd[t]; sWd[t + 256] = Wd[t + 256];
  __syncthreads();
  int wave = t >> 6, lane = t & 63;
  int n = blockIdx.x * 4 + wave;
  if (n >= N) return;
  uint2 uu = *(const uint2*)&hint[(size_t)n * 128 + lane * 2];
  float v0 = lo16f(uu.x) + hi16f(uu.x);
  float v1 = lo16f(uu.y) + hi16f(uu.y);
  float p[8];
#pragma unroll
  for (int hh = 0; hh < 4; ++hh) {
    p[hh]     = v0 * sWs[hh * 128 + 2 * lane] + v1 * sWs[hh * 128 + 2 * lane + 1];
    p[4 + hh] = v0 * sWd[hh * 128 + 2 * lane] + v1 * sWd[hh * 128 + 2 * lane + 1];
  }
#pragma unroll
  for (int off = 32; off; off >>= 1)
#pragma unroll
    for (int i = 0; i < 8; ++i) p[i] += __shfl_xor(p[i], off);
  if (lane == 0) {
#pragma unroll
    for (int hh = 0; hh < 4; ++hh) {
      al_src[n * 4 + hh] = p[hh];
      al_dst[n * 4 + hh] = p[4 + hh];
    }
  }
}

// ---------------------------------------------------------------------------
// aggregation v3: 2 nodes/wave (32-lane halves). Edges in chunks of 8:
// quad q computes edge (c0+q)'s logit for head (lane&3) -> 1 exp2/lane;
// 3-step shfl_xor chunk-max; unconditional chunk-granularity rescale;
// phase 2 broadcasts weights/index via shuffles, 8B fp16 gather + pk-FMA.
// ss accumulated redundantly per lane (no reduce). fp16 frag output.
// ---------------------------------------------------------------------------
__global__ __launch_bounds__(256) void agg_G_kernel(const ushort_t* __restrict__ h16,
                                                    const float* __restrict__ al_src,
                                                    const float* __restrict__ al_dst,
                                                    const int* __restrict__ rowptr,
                                                    const int* __restrict__ colbuf,
                                                    ushort_t* __restrict__ Gf, int N) {
  int wave = threadIdx.x >> 6, lane = threadIdx.x & 63;
  int hl = lane & 31;
  int half_base = lane & 32;      // absolute lane base of this 32-lane half
  int q = hl >> 2, hc = hl & 3;   // quad index, head class
  int qb = lane & ~3;             // absolute quad base
  int n = blockIdx.x * 8 + wave * 2 + (lane >> 5);
  bool alive = n < N;
  int beg = 0, d = 0;
  float ald_hc = 0.f;
  if (alive) {
    beg = rowptr[n];
    d = rowptr[n + 1] - beg;
    ald_hc = al_dst[(size_t)n * 4 + hc];
  }
  int dm1 = max(d - 1, 0);
  float m_run = -1e30f;
  f32x2 ss01 = {0.f, 0.f}, ss23 = {0.f, 0.f};
  f32x2 a0a = {0.f,0.f}, a0b = {0.f,0.f};
  f32x2 a1a = {0.f,0.f}, a1b = {0.f,0.f};
  f32x2 a2a = {0.f,0.f}, a2b = {0.f,0.f};
  f32x2 a3a = {0.f,0.f}, a3b = {0.f,0.f};

  for (int c0 = 0; c0 < d; c0 += 8) {
    int cn = min(8, d - c0);
    // ---- phase 1: one edge per quad, one head per lane ----
    int j = c0 + q;
    int sq = colbuf[beg + min(j, dm1)];
    float e = al_src[(size_t)sq * 4 + hc] + ald_hc;
    e = fmaxf(e, 0.2f * e);
    e = (q < cn) ? e : -1e30f;
    float mc = e;
    mc = fmaxf(mc, __shfl_xor(mc, 4));
    mc = fmaxf(mc, __shfl_xor(mc, 8));
    mc = fmaxf(mc, __shfl_xor(mc, 16));   // per-head max over the 8 edges
    float nm = fmaxf(m_run, mc);
    float fown = exp2f(m_run - nm);       // first chunk: exp2(-huge)=0
    m_run = nm;
    float w_own = (q < cn) ? exp2f(e - nm) : 0.f;
    float f0 = __shfl(fown, qb + 0), f1 = __shfl(fown, qb + 1);
    float f2 = __shfl(fown, qb + 2), f3 = __shfl(fown, qb + 3);
    ss01 *= f32x2{f0, f1}; ss23 *= f32x2{f2, f3};
    f32x2 F0 = {f0, f0}, F1 = {f1, f1}, F2 = {f2, f2}, F3 = {f3, f3};
    a0a *= F0; a0b *= F0; a1a *= F1; a1b *= F1;
    a2a *= F2; a2b *= F2; a3a *= F3; a3b *= F3;
    // ---- phase 2: broadcast weights + index, gather, FMA ----
    int s_c = __shfl(sq, half_base);
    ushort4v hv_c = *(const ushort4v*)&h16[(size_t)s_c * 128 + hl * 4];
    for (int jj = 0; jj < cn; ++jj) {
      int s_n = __shfl(sq, half_base + min(jj + 1, cn - 1) * 4);
      ushort4v hv_n = *(const ushort4v*)&h16[(size_t)s_n * 128 + hl * 4];
      int wb = half_base + jj * 4;
      float w0 = __shfl(w_own, wb + 0);
      float w1 = __shfl(w_own, wb + 1);
      float w2 = __shfl(w_own, wb + 2);
      float w3 = __shfl(w_own, wb + 3);
      ss01 += f32x2{w0, w1}; ss23 += f32x2{w2, w3};
      f32x2 v01 = {f16_to_f(hv_c[0]), f16_to_f(hv_c[1])};
      f32x2 v23 = {f16_to_f(hv_c[2]), f16_to_f(hv_c[3])};
      a0a += f32x2{w0, w0} * v01; a0b += f32x2{w0, w0} * v23;
      a1a += f32x2{w1, w1} * v01; a1b += f32x2{w1, w1} * v23;
      a2a += f32x2{w2, w2} * v01; a2b += f32x2{w2, w2} * v23;
      a3a += f32x2{w3, w3} * v01; a3b += f32x2{w3, w3} * v23;
      hv_c = hv_n;
    }
  }
  if (!alive) return;
  float g[4][4];
  float inv;
  inv = 1.f / (ss01.x + 1e-16f);
  g[0][0] = a0a.x * inv; g[0][1] = a0a.y * inv; g[0][2] = a0b.x * inv; g[0][3] = a0b.y * inv;
  inv = 1.f / (ss01.y + 1e-16f);
  g[1][0] = a1a.x * inv; g[1][1] = a1a.y * inv; g[1][2] = a1b.x * inv; g[1][3] = a1b.y * inv;
  inv = 1.f / (ss23.x + 1e-16f);
  g[2][0] = a2a.x * inv; g[2][1] = a2a.y * inv; g[2][2] = a2b.x * inv; g[2][3] = a2b.y * inv;
  inv = 1.f / (ss23.y + 1e-16f);
  g[3][0] = a3a.x * inv; g[3][1] = a3a.y * inv; g[3][2] = a3b.x * inv; g[3][3] = a3b.y * inv;
#pragma unroll
  for (int h = 0; h < 4; ++h) {
    ushort_t q0 = f_to_f16(g[h][0]), q1 = f_to_f16(g[h][1]);
    ushort_t q2 = f_to_f16(g[h][2]), q3 = f_to_f16(g[h][3]);
    size_t o = ((size_t)(n >> 4) * 64 + h * 16 + (hl >> 1)) * 128 + (n & 15) * 8 + (hl & 1) * 4;
    *(uint2*)&Gf[o] = make_uint2((uint_t)q0 | ((uint_t)q1 << 16),
                                 (uint_t)q2 | ((uint_t)q3 << 16));
  }
}

// ---------------------------------------------------------------------------
// Barrier-free fp16 MFMA GEMM from fragment-layout inputs. Compile-time K/MODE.
// 4 waves/block, 16 rows/wave, single MFMA pass (fp32 accumulate).
// MODE 0: packed-uint + fp16 row out (relu); 1: fp16 frag out (relu);
// MODE 2: fp32 row out (no relu).
// ---------------------------------------------------------------------------
template <int K, int MODE>
__global__ __launch_bounds__(256) void gemm_frag_kernel(
    const ushort_t* __restrict__ Af, const ushort_t* __restrict__ Bf,
    uint_t* __restrict__ Ci, ushort_t* __restrict__ H16,
    ushort_t* __restrict__ Cf16, float* __restrict__ Cf,
    int M, const float* __restrict__ bias) {
  constexpr int KT = K >> 5;
  constexpr int PS = 16 * K;          // panel stride (ushorts)
  int lane = threadIdx.x & 63;
  int wid = blockIdx.x * 4 + (threadIdx.x >> 6);
  int krow = lane >> 4, ml = lane & 15;
  int lb = krow * 128 + ml * 8;
  size_t abase = (size_t)wid * PS + lb;
  f32x4 acc[8] = {};
  half8 a_c = *(const half8*)&Af[abase];
#pragma unroll
  for (int kt = 0; kt < KT; ++kt) {
    half8 a_n = a_c;
    if (kt + 1 < KT) a_n = *(const half8*)&Af[abase + (kt + 1) * 512];
    half8 b[8];
#pragma unroll
    for (int j = 0; j < 8; ++j)
      b[j] = *(const half8*)&Bf[j * PS + kt * 512 + lb];
#pragma unroll
    for (int j = 0; j < 8; ++j)
      acc[j] = __builtin_amdgcn_mfma_f32_16x16x32_f16(a_c, b[j], acc[j], 0, 0, 0);
    a_c = a_n;
  }
  int wrow0 = wid * 16;
#pragma unroll
  for (int j = 0; j < 8; ++j) {
    int col = j * 16 + ml;
    float bv = bias[col];
#pragma unroll
    for (int r = 0; r < 4; ++r) {
      int row = wrow0 + krow * 4 + r;
      if (row < M) {
        float v = acc[j][r] + bv;
        if (MODE != 2) v = fmaxf(v, 0.f);
        if (MODE == 0) {
          Ci[(size_t)row * 128 + col] = pack_hl(v);
          H16[(size_t)row * 128 + col] = f_to_f16(v);
        } else if (MODE == 1) {
          size_t o = ((size_t)(row >> 4) * 16 + (col >> 3)) * 128 + (row & 15) * 8 + (col & 7);
          Cf16[o] = f_to_f16(v);
        } else {
          Cf[(size_t)row * 128 + col] = v;
        }
      }
    }
  }
}

// ---------------------------------------------------------------------------
extern "C" void kernel_launch(void* const* d_in, const int* in_sizes, int n_in,
                              void* d_out, int out_size, void* d_ws, size_t ws_size,
                              hipStream_t stream) {
  const float* x  = (const float*)d_in[0];
  const int*   ei = (const int*)d_in[1];
  const float* Wl[3]  = {(const float*)d_in[2], (const float*)d_in[6], (const float*)d_in[10]};
  const float* asr[3] = {(const float*)d_in[3], (const float*)d_in[7], (const float*)d_in[11]};
  const float* adr[3] = {(const float*)d_in[4], (const float*)d_in[8], (const float*)d_in[12]};
  const float* bl[3]  = {(const float*)d_in[5], (const float*)d_in[9], (const float*)d_in[13]};
  const float* Wp = (const float*)d_in[14];
  const float* bp = (const float*)d_in[15];

  const int N = in_sizes[0] / 128;   // 50000
  const int E = in_sizes[1] / 2;     // 400000
  const int EN = E + N;
  const int Mtiles = (N + 127) / 128;  // 391
  const int Mp = Mtiles * 128;         // 50048
  const int NB = (N + 255) / 256;
  const int NPB = Mp / 16 / 4;         // 782 GEMM blocks

  char* ws = (char*)d_ws;
  size_t off = 0;
  auto carve = [&](size_t bytes) -> void* {
    void* p = ws + off;
    off = (off + bytes + 255) & ~(size_t)255;
    return p;
  };
  ushort_t* Gf    = (ushort_t*)carve((size_t)Mp * 512 * 2);  // fp16 frag layout
  uint_t*   hiA   = (uint_t*)carve((size_t)N * 128 * 4);     // packed hi/lo (al)
  uint_t*   hiB   = (uint_t*)carve((size_t)N * 128 * 4);
  ushort_t* h16   = (ushort_t*)carve((size_t)N * 128 * 2);   // fp16 (agg gather)
  ushort_t* h3f   = (ushort_t*)carve((size_t)Mp * 128 * 2);  // fp16 frag (proj input)
  ushort_t* wsf   = (ushort_t*)carve((size_t)128 * 512 * 2); // fp16 frag Wstack / Wp
  float*    alsrc = (float*)carve((size_t)N * 4 * 4);
  float*    aldst = (float*)carve((size_t)N * 4 * 4);
  float*    Wsb   = (float*)carve(512 * 4);
  float*    Wdb   = (float*)carve(512 * 4);
  int*      rowptr= (int*)carve((size_t)(N + 1) * 4);
  int*      deg   = (int*)carve((size_t)N * 4);
  int*      bsum  = (int*)carve(256 * 4);
  int*      fillc = (int*)carve((size_t)N * 4);
  int*      colbuf= (int*)carve((size_t)EN * 4);
  int*      flag  = (int*)carve(256);

  // ---- CSR build ----
  detect_i64_kernel<<<1, 64, 0, stream>>>(ei, flag);
  hipMemsetAsync(deg, 0, (size_t)N * 4, stream);
  hipMemsetAsync(fillc, 0, (size_t)N * 4, stream);
  int ebl = (EN + 255) / 256;
  deg_kernel<<<ebl, 256, 0, stream>>>(ei, flag, E, N, deg);
  scan_blk_kernel<<<NB, 256, 0, stream>>>(deg, rowptr, bsum, N);
  scan_top_kernel<<<1, 256, 0, stream>>>(bsum, NB);
  scan_add_kernel<<<NB, 256, 0, stream>>>(rowptr, bsum, N);
  fill_kernel<<<ebl, 256, 0, stream>>>(ei, flag, E, N, rowptr, fillc, colbuf);

  // ---- split x into packed + fp16 ----
  const int n_real = N * 128;
  split_x_i_kernel<<<(n_real / 4 + 255) / 256, 256, 0, stream>>>(x, hiA, h16, n_real);

  // ---- 3 GAT layers ----
  uint_t* hin = hiA;
  uint_t* hnext = hiB;
  for (int L = 0; L < 3; ++L) {
    wsd_kernel<<<32, 256, 0, stream>>>(Wl[L], asr[L], adr[L], Wsb, Wdb);
    al_kernel_i<<<(N + 3) / 4, 256, 0, stream>>>(hin, Wsb, Wdb, alsrc, aldst, N);
    agg_G_kernel<<<Mp / 8, 256, 0, stream>>>(h16, alsrc, aldst,
                                             rowptr, colbuf, Gf, N);
    split_wstack_frag_kernel<<<256, 256, 0, stream>>>(Wl[L], wsf);
    if (L < 2) {
      gemm_frag_kernel<512, 0><<<NPB, 256, 0, stream>>>(Gf, wsf,
                                                        hnext, h16, nullptr, nullptr,
                                                        N, bl[L]);
      uint_t* t = hin; hin = hnext; hnext = t;
    } else {
      gemm_frag_kernel<512, 1><<<NPB, 256, 0, stream>>>(Gf, wsf,
                                                        nullptr, nullptr, h3f, nullptr,
                                                        N, bl[L]);
    }
  }

  // ---- final projection: out = h3 @ Wp + bp ----
  split_wt_frag_kernel<<<64, 256, 0, stream>>>(Wp, wsf);
  gemm_frag_kernel<128, 2><<<NPB, 256, 0, stream>>>(h3f, wsf,
                                                    nullptr, nullptr, nullptr, (float*)d_out,
                                                    N, bp);
}

// Round 15
// 329.649 us; speedup vs baseline: 1.2904x; 1.2177x over previous
//
#include <hip/hip_runtime.h>
#include <cstddef>
#include <cstdint>

typedef _Float16 half8 __attribute__((ext_vector_type(8)));
typedef float f32x4 __attribute__((ext_vector_type(4)));
typedef float f32x2 __attribute__((ext_vector_type(2)));
typedef unsigned short ushort_t;
typedef unsigned int uint_t;
typedef ushort_t ushort4v __attribute__((ext_vector_type(4)));
typedef float f32x4v __attribute__((ext_vector_type(4)));

#define INV_LN2 1.4426950408889634f

__device__ __forceinline__ ushort_t f_to_f16(float f) {
  _Float16 h = (_Float16)f;
  union { _Float16 h; ushort_t u; } v; v.h = h; return v.u;
}
__device__ __forceinline__ float f16_to_f(ushort_t u) {
  union { ushort_t u; _Float16 h; } v; v.u = u; return (float)v.h;
}

// ---------------------------------------------------------------------------
// CSR build
// ---------------------------------------------------------------------------
__global__ __launch_bounds__(64) void detect_i64_kernel(const int* __restrict__ ei,
                                                        int* __restrict__ flag) {
  if (threadIdx.x == 0) {
    int is32 = 0;
    for (int i = 1; i < 1001; i += 2) {
      if (ei[i] != 0) { is32 = 1; break; }
    }
    *flag = is32;
  }
}

__device__ __forceinline__ int load_src(const int* ei, int is32, int E, int e) {
  return is32 ? ei[e] : ei[2 * e];
}
__device__ __forceinline__ int load_dst(const int* ei, int is32, int E, int e) {
  return is32 ? ei[E + e] : ei[2 * (E + e)];
}

__global__ __launch_bounds__(256) void deg_kernel(const int* __restrict__ ei,
                                                  const int* __restrict__ flag,
                                                  int E, int N, int* __restrict__ deg) {
  int e = blockIdx.x * 256 + threadIdx.x;
  if (e >= E + N) return;
  int d = (e < E) ? load_dst(ei, *flag, E, e) : (e - E);
  atomicAdd(&deg[d], 1);
}

__global__ __launch_bounds__(256) void scan_blk_kernel(const int* __restrict__ deg,
                                                       int* __restrict__ rowptr,
                                                       int* __restrict__ bsum, int N) {
  __shared__ int buf[256];
  int b = blockIdx.x, t = threadIdx.x, i = b * 256 + t;
  int v = (i < N) ? deg[i] : 0;
  buf[t] = v;
  __syncthreads();
  for (int off = 1; off < 256; off <<= 1) {
    int add = (t >= off) ? buf[t - off] : 0;
    __syncthreads();
    buf[t] += add;
    __syncthreads();
  }
  if (i < N) rowptr[i + 1] = buf[t];
  if (t == 255) bsum[b] = buf[255];
  if (b == 0 && t == 0) rowptr[0] = 0;
}

__global__ __launch_bounds__(256) void scan_top_kernel(int* __restrict__ bsum, int NB) {
  __shared__ int buf[256];
  int t = threadIdx.x;
  int v = (t < NB) ? bsum[t] : 0;
  buf[t] = v;
  __syncthreads();
  for (int off = 1; off < 256; off <<= 1) {
    int add = (t >= off) ? buf[t - off] : 0;
    __syncthreads();
    buf[t] += add;
    __syncthreads();
  }
  if (t < NB) bsum[t] = buf[t];
}

__global__ __launch_bounds__(256) void scan_add_kernel(int* __restrict__ rowptr,
                                                       const int* __restrict__ bsum, int N) {
  int b = blockIdx.x, t = threadIdx.x, i = b * 256 + t;
  if (b > 0 && i < N) rowptr[i + 1] += bsum[b - 1];
}

__global__ __launch_bounds__(256) void fill_kernel(const int* __restrict__ ei,
                                                   const int* __restrict__ flag,
                                                   int E, int N,
                                                   const int* __restrict__ rowptr,
                                                   int* __restrict__ fillc,
                                                   int* __restrict__ colbuf) {
  int e = blockIdx.x * 256 + threadIdx.x;
  if (e >= E + N) return;
  int s, d;
  if (e < E) { int is32 = *flag; s = load_src(ei, is32, E, e); d = load_dst(ei, is32, E, e); }
  else { s = e - E; d = s; }
  int pos = atomicAdd(&fillc[d], 1);
  colbuf[rowptr[d] + pos] = s;
}

// ---------------------------------------------------------------------------
// prep kernels
// ---------------------------------------------------------------------------
// fp32 x -> fp16 h16 (agg gather buffer)
__global__ __launch_bounds__(256) void split_x16_kernel(const float* __restrict__ h,
                                                        ushort_t* __restrict__ h16,
                                                        int n) {
  int i = (blockIdx.x * 256 + threadIdx.x) * 4;
  if (i >= n) return;
  f32x4v v = *(const f32x4v*)&h[i];
  ushort4v s;
  s[0] = f_to_f16(v[0]); s[1] = f_to_f16(v[1]);
  s[2] = f_to_f16(v[2]); s[3] = f_to_f16(v[3]);
  *(ushort4v*)&h16[i] = s;
}

// Wp [k=128][col=128] fp32 -> fp16 frag layout
__global__ __launch_bounds__(256) void split_wt_frag_kernel(const float* __restrict__ W,
                                                            ushort_t* __restrict__ Wf) {
  int t = blockIdx.x * 256 + threadIdx.x;   // 16384
  int blk = t >> 7, rem = t & 127;
  int c16 = blk >> 4, k8 = blk & 15;
  int cl = rem >> 3, kl = rem & 7;
  int col = c16 * 16 + cl, k = k8 * 8 + kl;
  Wf[t] = f_to_f16(W[(size_t)k * 128 + col]);
}

// W [128][512] -> Wstack fp16 frag layout (K=512), val = 0.25*W[f][h*128+col]
__global__ __launch_bounds__(256) void split_wstack_frag_kernel(const float* __restrict__ W,
                                                                ushort_t* __restrict__ Wf) {
  int t = blockIdx.x * 256 + threadIdx.x;   // 65536
  int c16 = t >> 13;
  int r = t & 8191;
  int k8 = r >> 7;
  int rem = r & 127;
  int rl = rem >> 3, kl = rem & 7;
  int col = c16 * 16 + rl;
  int k = k8 * 8 + kl;
  int h = k >> 7, f = k & 127;
  Wf[t] = f_to_f16(0.25f * W[(size_t)f * 512 + h * 128 + col]);
}

// Ws = (1/ln2) * W-folded attention vectors, two layouts:
// Ws4[f*4+h] (for GEMM-epilogue float4 loads) and Wsh[h*128+f] (layer-0 al LDS)
__global__ __launch_bounds__(256) void wsd_kernel(const float* __restrict__ W,
                                                  const float* __restrict__ a_src,
                                                  const float* __restrict__ a_dst,
                                                  float* __restrict__ Ws4,
                                                  float* __restrict__ Wd4,
                                                  float* __restrict__ Wsh,
                                                  float* __restrict__ Wdh) {
  int wave = threadIdx.x >> 6, lane = threadIdx.x & 63;
  int f = blockIdx.x * 4 + wave;          // grid = 32 -> f in [0,128)
  int base = lane * 8;
  float4 w0 = *(const float4*)&W[(size_t)f * 512 + base];
  float4 w1 = *(const float4*)&W[(size_t)f * 512 + base + 4];
  float4 s0 = *(const float4*)&a_src[base];
  float4 s1 = *(const float4*)&a_src[base + 4];
  float4 d0 = *(const float4*)&a_dst[base];
  float4 d1 = *(const float4*)&a_dst[base + 4];
  float ps = w0.x*s0.x + w0.y*s0.y + w0.z*s0.z + w0.w*s0.w
           + w1.x*s1.x + w1.y*s1.y + w1.z*s1.z + w1.w*s1.w;
  float pd = w0.x*d0.x + w0.y*d0.y + w0.z*d0.z + w0.w*d0.w
           + w1.x*d1.x + w1.y*d1.y + w1.z*d1.z + w1.w*d1.w;
#pragma unroll
  for (int off = 1; off <= 8; off <<= 1) {
    ps += __shfl_xor(ps, off);
    pd += __shfl_xor(pd, off);
  }
  if ((lane & 15) == 0) {
    int h = lane >> 4;
    float vs = ps * INV_LN2, vd = pd * INV_LN2;
    Ws4[f * 4 + h] = vs;
    Wd4[f * 4 + h] = vd;
    Wsh[h * 128 + f] = vs;
    Wdh[h * 128 + f] = vd;
  }
}

// layer-0 al from fp32 x. One wave per node; Ws/Wd in [h][128] layout.
__global__ __launch_bounds__(256) void al_x_kernel(const float* __restrict__ x,
                                                   const float* __restrict__ Wsh,
                                                   const float* __restrict__ Wdh,
                                                   float* __restrict__ al_src,
                                                   float* __restrict__ al_dst, int N) {
  __shared__ float sWs[512], sWd[512];
  int t = threadIdx.x;
  sWs[t] = Wsh[t]; sWs[t + 256] = Wsh[t + 256];
  sWd[t] = Wdh[t]; sWd[t + 256] = Wdh[t + 256];
  __syncthreads();
  int wave = t >> 6, lane = t & 63;
  int n = blockIdx.x * 4 + wave;
  if (n >= N) return;
  float2 hv = *(const float2*)&x[(size_t)n * 128 + lane * 2];
  float p[8];
#pragma unroll
  for (int hh = 0; hh < 4; ++hh) {
    p[hh]     = hv.x * sWs[hh * 128 + 2 * lane] + hv.y * sWs[hh * 128 + 2 * lane + 1];
    p[4 + hh] = hv.x * sWd[hh * 128 + 2 * lane] + hv.y * sWd[hh * 128 + 2 * lane + 1];
  }
#pragma unroll
  for (int off = 32; off; off >>= 1)
#pragma unroll
    for (int i = 0; i < 8; ++i) p[i] += __shfl_xor(p[i], off);
  if (lane == 0) {
#pragma unroll
    for (int hh = 0; hh < 4; ++hh) {
      al_src[n * 4 + hh] = p[hh];
      al_dst[n * 4 + hh] = p[4 + hh];
    }
  }
}

// ---------------------------------------------------------------------------
// aggregation v3 (unchanged from round 14): 2 nodes/wave, chunks of 8 edges,
// quad-specialized logits (1 exp2/lane), chunk-granularity rescale, shuffled
// weight broadcast, fp16 gather + pk-FMA. fp16 frag output.
// ---------------------------------------------------------------------------
__global__ __launch_bounds__(256) void agg_G_kernel(const ushort_t* __restrict__ h16,
                                                    const float* __restrict__ al_src,
                                                    const float* __restrict__ al_dst,
                                                    const int* __restrict__ rowptr,
                                                    const int* __restrict__ colbuf,
                                                    ushort_t* __restrict__ Gf, int N) {
  int wave = threadIdx.x >> 6, lane = threadIdx.x & 63;
  int hl = lane & 31;
  int half_base = lane & 32;
  int q = hl >> 2, hc = hl & 3;
  int qb = lane & ~3;
  int n = blockIdx.x * 8 + wave * 2 + (lane >> 5);
  bool alive = n < N;
  int beg = 0, d = 0;
  float ald_hc = 0.f;
  if (alive) {
    beg = rowptr[n];
    d = rowptr[n + 1] - beg;
    ald_hc = al_dst[(size_t)n * 4 + hc];
  }
  int dm1 = max(d - 1, 0);
  float m_run = -1e30f;
  f32x2 ss01 = {0.f, 0.f}, ss23 = {0.f, 0.f};
  f32x2 a0a = {0.f,0.f}, a0b = {0.f,0.f};
  f32x2 a1a = {0.f,0.f}, a1b = {0.f,0.f};
  f32x2 a2a = {0.f,0.f}, a2b = {0.f,0.f};
  f32x2 a3a = {0.f,0.f}, a3b = {0.f,0.f};

  for (int c0 = 0; c0 < d; c0 += 8) {
    int cn = min(8, d - c0);
    int j = c0 + q;
    int sq = colbuf[beg + min(j, dm1)];
    float e = al_src[(size_t)sq * 4 + hc] + ald_hc;
    e = fmaxf(e, 0.2f * e);
    e = (q < cn) ? e : -1e30f;
    float mc = e;
    mc = fmaxf(mc, __shfl_xor(mc, 4));
    mc = fmaxf(mc, __shfl_xor(mc, 8));
    mc = fmaxf(mc, __shfl_xor(mc, 16));
    float nm = fmaxf(m_run, mc);
    float fown = exp2f(m_run - nm);
    m_run = nm;
    float w_own = (q < cn) ? exp2f(e - nm) : 0.f;
    float f0 = __shfl(fown, qb + 0), f1 = __shfl(fown, qb + 1);
    float f2 = __shfl(fown, qb + 2), f3 = __shfl(fown, qb + 3);
    ss01 *= f32x2{f0, f1}; ss23 *= f32x2{f2, f3};
    f32x2 F0 = {f0, f0}, F1 = {f1, f1}, F2 = {f2, f2}, F3 = {f3, f3};
    a0a *= F0; a0b *= F0; a1a *= F1; a1b *= F1;
    a2a *= F2; a2b *= F2; a3a *= F3; a3b *= F3;
    int s_c = __shfl(sq, half_base);
    ushort4v hv_c = *(const ushort4v*)&h16[(size_t)s_c * 128 + hl * 4];
    for (int jj = 0; jj < cn; ++jj) {
      int s_n = __shfl(sq, half_base + min(jj + 1, cn - 1) * 4);
      ushort4v hv_n = *(const ushort4v*)&h16[(size_t)s_n * 128 + hl * 4];
      int wb = half_base + jj * 4;
      float w0 = __shfl(w_own, wb + 0);
      float w1 = __shfl(w_own, wb + 1);
      float w2 = __shfl(w_own, wb + 2);
      float w3 = __shfl(w_own, wb + 3);
      ss01 += f32x2{w0, w1}; ss23 += f32x2{w2, w3};
      f32x2 v01 = {f16_to_f(hv_c[0]), f16_to_f(hv_c[1])};
      f32x2 v23 = {f16_to_f(hv_c[2]), f16_to_f(hv_c[3])};
      a0a += f32x2{w0, w0} * v01; a0b += f32x2{w0, w0} * v23;
      a1a += f32x2{w1, w1} * v01; a1b += f32x2{w1, w1} * v23;
      a2a += f32x2{w2, w2} * v01; a2b += f32x2{w2, w2} * v23;
      a3a += f32x2{w3, w3} * v01; a3b += f32x2{w3, w3} * v23;
      hv_c = hv_n;
    }
  }
  if (!alive) return;
  float g[4][4];
  float inv;
  inv = 1.f / (ss01.x + 1e-16f);
  g[0][0] = a0a.x * inv; g[0][1] = a0a.y * inv; g[0][2] = a0b.x * inv; g[0][3] = a0b.y * inv;
  inv = 1.f / (ss01.y + 1e-16f);
  g[1][0] = a1a.x * inv; g[1][1] = a1a.y * inv; g[1][2] = a1b.x * inv; g[1][3] = a1b.y * inv;
  inv = 1.f / (ss23.x + 1e-16f);
  g[2][0] = a2a.x * inv; g[2][1] = a2a.y * inv; g[2][2] = a2b.x * inv; g[2][3] = a2b.y * inv;
  inv = 1.f / (ss23.y + 1e-16f);
  g[3][0] = a3a.x * inv; g[3][1] = a3a.y * inv; g[3][2] = a3b.x * inv; g[3][3] = a3b.y * inv;
#pragma unroll
  for (int h = 0; h < 4; ++h) {
    ushort_t q0 = f_to_f16(g[h][0]), q1 = f_to_f16(g[h][1]);
    ushort_t q2 = f_to_f16(g[h][2]), q3 = f_to_f16(g[h][3]);
    size_t o = ((size_t)(n >> 4) * 64 + h * 16 + (hl >> 1)) * 128 + (n & 15) * 8 + (hl & 1) * 4;
    *(uint2*)&Gf[o] = make_uint2((uint_t)q0 | ((uint_t)q1 << 16),
                                 (uint_t)q2 | ((uint_t)q3 << 16));
  }
}

// ---------------------------------------------------------------------------
// Barrier-free fp16 MFMA GEMM. Compile-time K/MODE. 4 waves/block, 16 rows/wave.
// MODE 0: fp16 row out (relu) + FUSED next-layer al_src/al_dst computation;
// MODE 1: fp16 frag out (relu); MODE 2: fp32 row out (no relu).
// ---------------------------------------------------------------------------
template <int K, int MODE>
__global__ __launch_bounds__(256) void gemm_frag_kernel(
    const ushort_t* __restrict__ Af, const ushort_t* __restrict__ Bf,
    ushort_t* __restrict__ H16, ushort_t* __restrict__ Cf16, float* __restrict__ Cf,
    const float* __restrict__ WsN, const float* __restrict__ WdN,
    float* __restrict__ alS, float* __restrict__ alD,
    int M, const float* __restrict__ bias) {
  constexpr int KT = K >> 5;
  constexpr int PS = 16 * K;          // panel stride (ushorts)
  int lane = threadIdx.x & 63;
  int wid = blockIdx.x * 4 + (threadIdx.x >> 6);
  int krow = lane >> 4, ml = lane & 15;
  int lb = krow * 128 + ml * 8;
  size_t abase = (size_t)wid * PS + lb;
  f32x4 acc[8] = {};
  half8 a_c = *(const half8*)&Af[abase];
#pragma unroll
  for (int kt = 0; kt < KT; ++kt) {
    half8 a_n = a_c;
    if (kt + 1 < KT) a_n = *(const half8*)&Af[abase + (kt + 1) * 512];
    half8 b[8];
#pragma unroll
    for (int j = 0; j < 8; ++j)
      b[j] = *(const half8*)&Bf[j * PS + kt * 512 + lb];
#pragma unroll
    for (int j = 0; j < 8; ++j)
      acc[j] = __builtin_amdgcn_mfma_f32_16x16x32_f16(a_c, b[j], acc[j], 0, 0, 0);
    a_c = a_n;
  }
  int wrow0 = wid * 16;
  if (MODE == 0) {
    float ps[4][4] = {};   // [hh][r]
    float pd[4][4] = {};
#pragma unroll
    for (int j = 0; j < 8; ++j) {
      int col = j * 16 + ml;
      float bv = bias[col];
      float4 w4s = *(const float4*)&WsN[col * 4];
      float4 w4d = *(const float4*)&WdN[col * 4];
#pragma unroll
      for (int r = 0; r < 4; ++r) {
        int row = wrow0 + krow * 4 + r;
        float v = fmaxf(acc[j][r] + bv, 0.f);
        if (row < M) H16[(size_t)row * 128 + col] = f_to_f16(v);
        ps[0][r] += v * w4s.x; ps[1][r] += v * w4s.y;
        ps[2][r] += v * w4s.z; ps[3][r] += v * w4s.w;
        pd[0][r] += v * w4d.x; pd[1][r] += v * w4d.y;
        pd[2][r] += v * w4d.z; pd[3][r] += v * w4d.w;
      }
    }
    // reduce over the 16 ml-lanes (same krow group holds full rows)
#pragma unroll
    for (int off = 1; off <= 8; off <<= 1) {
#pragma unroll
      for (int hh = 0; hh < 4; ++hh)
#pragma unroll
        for (int r = 0; r < 4; ++r) {
          ps[hh][r] += __shfl_xor(ps[hh][r], off);
          pd[hh][r] += __shfl_xor(pd[hh][r], off);
        }
    }
    if (ml == 0) {
#pragma unroll
      for (int r = 0; r < 4; ++r) {
        int row = wrow0 + krow * 4 + r;
        if (row < M) {
#pragma unroll
          for (int hh = 0; hh < 4; ++hh) {
            alS[row * 4 + hh] = ps[hh][r];
            alD[row * 4 + hh] = pd[hh][r];
          }
        }
      }
    }
  } else {
#pragma unroll
    for (int j = 0; j < 8; ++j) {
      int col = j * 16 + ml;
      float bv = bias[col];
#pragma unroll
      for (int r = 0; r < 4; ++r) {
        int row = wrow0 + krow * 4 + r;
        if (row < M) {
          float v = acc[j][r] + bv;
          if (MODE != 2) v = fmaxf(v, 0.f);
          if (MODE == 1) {
            size_t o = ((size_t)(row >> 4) * 16 + (col >> 3)) * 128 + (row & 15) * 8 + (col & 7);
            Cf16[o] = f_to_f16(v);
          } else {
            Cf[(size_t)row * 128 + col] = v;
          }
        }
      }
    }
  }
}

// ---------------------------------------------------------------------------
extern "C" void kernel_launch(void* const* d_in, const int* in_sizes, int n_in,
                              void* d_out, int out_size, void* d_ws, size_t ws_size,
                              hipStream_t stream) {
  const float* x  = (const float*)d_in[0];
  const int*   ei = (const int*)d_in[1];
  const float* Wl[3]  = {(const float*)d_in[2], (const float*)d_in[6], (const float*)d_in[10]};
  const float* asr[3] = {(const float*)d_in[3], (const float*)d_in[7], (const float*)d_in[11]};
  const float* adr[3] = {(const float*)d_in[4], (const float*)d_in[8], (const float*)d_in[12]};
  const float* bl[3]  = {(const float*)d_in[5], (const float*)d_in[9], (const float*)d_in[13]};
  const float* Wp = (const float*)d_in[14];
  const float* bp = (const float*)d_in[15];

  const int N = in_sizes[0] / 128;   // 50000
  const int E = in_sizes[1] / 2;     // 400000
  const int EN = E + N;
  const int Mtiles = (N + 127) / 128;  // 391
  const int Mp = Mtiles * 128;         // 50048
  const int NB = (N + 255) / 256;
  const int NPB = Mp / 16 / 4;         // 782 GEMM blocks

  char* ws = (char*)d_ws;
  size_t off = 0;
  auto carve = [&](size_t bytes) -> void* {
    void* p = ws + off;
    off = (off + bytes + 255) & ~(size_t)255;
    return p;
  };
  ushort_t* Gf    = (ushort_t*)carve((size_t)Mp * 512 * 2);  // fp16 frag layout
  ushort_t* h16   = (ushort_t*)carve((size_t)N * 128 * 2);   // fp16 h (agg gather)
  ushort_t* h3f   = (ushort_t*)carve((size_t)Mp * 128 * 2);  // fp16 frag (proj input)
  ushort_t* wsf   = (ushort_t*)carve((size_t)128 * 512 * 2); // fp16 frag Wstack / Wp
  float*    alsrc = (float*)carve((size_t)N * 4 * 4);
  float*    aldst = (float*)carve((size_t)N * 4 * 4);
  float*    Ws4   = (float*)carve(3 * 512 * 4);
  float*    Wd4   = (float*)carve(3 * 512 * 4);
  float*    Wsh   = (float*)carve(3 * 512 * 4);
  float*    Wdh   = (float*)carve(3 * 512 * 4);
  int*      rowptr= (int*)carve((size_t)(N + 1) * 4);
  int*      deg   = (int*)carve((size_t)N * 4);
  int*      bsum  = (int*)carve(256 * 4);
  int*      fillc = (int*)carve((size_t)N * 4);
  int*      colbuf= (int*)carve((size_t)EN * 4);
  int*      flag  = (int*)carve(256);

  // ---- CSR build ----
  detect_i64_kernel<<<1, 64, 0, stream>>>(ei, flag);
  hipMemsetAsync(deg, 0, (size_t)N * 4, stream);
  hipMemsetAsync(fillc, 0, (size_t)N * 4, stream);
  int ebl = (EN + 255) / 256;
  deg_kernel<<<ebl, 256, 0, stream>>>(ei, flag, E, N, deg);
  scan_blk_kernel<<<NB, 256, 0, stream>>>(deg, rowptr, bsum, N);
  scan_top_kernel<<<1, 256, 0, stream>>>(bsum, NB);
  scan_add_kernel<<<NB, 256, 0, stream>>>(rowptr, bsum, N);
  fill_kernel<<<ebl, 256, 0, stream>>>(ei, flag, E, N, rowptr, fillc, colbuf);

  // ---- x -> fp16 + folded attention vectors for all layers ----
  const int n_real = N * 128;
  split_x16_kernel<<<(n_real / 4 + 255) / 256, 256, 0, stream>>>(x, h16, n_real);
  for (int L = 0; L < 3; ++L)
    wsd_kernel<<<32, 256, 0, stream>>>(Wl[L], asr[L], adr[L],
                                       Ws4 + L * 512, Wd4 + L * 512,
                                       Wsh + L * 512, Wdh + L * 512);
  al_x_kernel<<<(N + 3) / 4, 256, 0, stream>>>(x, Wsh, Wdh, alsrc, aldst, N);

  // ---- 3 GAT layers ----
  for (int L = 0; L < 3; ++L) {
    agg_G_kernel<<<Mp / 8, 256, 0, stream>>>(h16, alsrc, aldst,
                                             rowptr, colbuf, Gf, N);
    split_wstack_frag_kernel<<<256, 256, 0, stream>>>(Wl[L], wsf);
    if (L < 2) {
      gemm_frag_kernel<512, 0><<<NPB, 256, 0, stream>>>(Gf, wsf,
                                                        h16, nullptr, nullptr,
                                                        Ws4 + (L + 1) * 512, Wd4 + (L + 1) * 512,
                                                        alsrc, aldst, N, bl[L]);
    } else {
      gemm_frag_kernel<512, 1><<<NPB, 256, 0, stream>>>(Gf, wsf,
                                                        nullptr, h3f, nullptr,
                                                        nullptr, nullptr, nullptr, nullptr,
                                                        N, bl[L]);
    }
  }

  // ---- final projection: out = h3 @ Wp + bp ----
  split_wt_frag_kernel<<<64, 256, 0, stream>>>(Wp, wsf);
  gemm_frag_kernel<128, 2><<<NPB, 256, 0, stream>>>(h3f, wsf,
                                                    nullptr, nullptr, (float*)d_out,
                                                    nullptr, nullptr, nullptr, nullptr,
                                                    N, bp);
}

// Round 16
// 312.831 us; speedup vs baseline: 1.3598x; 1.0538x over previous
//
#include <hip/hip_runtime.h>
#include <cstddef>
#include <cstdint>

typedef _Float16 half8 __attribute__((ext_vector_type(8)));
typedef float f32x4 __attribute__((ext_vector_type(4)));
typedef float f32x2 __attribute__((ext_vector_type(2)));
typedef unsigned short ushort_t;
typedef unsigned int uint_t;
typedef ushort_t ushort4v __attribute__((ext_vector_type(4)));
typedef float f32x4v __attribute__((ext_vector_type(4)));

#define INV_LN2 1.4426950408889634f

__device__ __forceinline__ ushort_t f_to_f16(float f) {
  _Float16 h = (_Float16)f;
  union { _Float16 h; ushort_t u; } v; v.h = h; return v.u;
}
__device__ __forceinline__ float f16_to_f(ushort_t u) {
  union { ushort_t u; _Float16 h; } v; v.u = u; return (float)v.h;
}

// ---------------------------------------------------------------------------
// CSR build
// ---------------------------------------------------------------------------
__global__ __launch_bounds__(64) void detect_i64_kernel(const int* __restrict__ ei,
                                                        int* __restrict__ flag) {
  if (threadIdx.x == 0) {
    int is32 = 0;
    for (int i = 1; i < 1001; i += 2) {
      if (ei[i] != 0) { is32 = 1; break; }
    }
    *flag = is32;
  }
}

__device__ __forceinline__ int load_src(const int* ei, int is32, int E, int e) {
  return is32 ? ei[e] : ei[2 * e];
}
__device__ __forceinline__ int load_dst(const int* ei, int is32, int E, int e) {
  return is32 ? ei[E + e] : ei[2 * (E + e)];
}

__global__ __launch_bounds__(256) void deg_kernel(const int* __restrict__ ei,
                                                  const int* __restrict__ flag,
                                                  int E, int N, int* __restrict__ deg) {
  int e = blockIdx.x * 256 + threadIdx.x;
  if (e >= E + N) return;
  int d = (e < E) ? load_dst(ei, *flag, E, e) : (e - E);
  atomicAdd(&deg[d], 1);
}

__global__ __launch_bounds__(256) void scan_blk_kernel(const int* __restrict__ deg,
                                                       int* __restrict__ rowptr,
                                                       int* __restrict__ bsum, int N) {
  __shared__ int buf[256];
  int b = blockIdx.x, t = threadIdx.x, i = b * 256 + t;
  int v = (i < N) ? deg[i] : 0;
  buf[t] = v;
  __syncthreads();
  for (int off = 1; off < 256; off <<= 1) {
    int add = (t >= off) ? buf[t - off] : 0;
    __syncthreads();
    buf[t] += add;
    __syncthreads();
  }
  if (i < N) rowptr[i + 1] = buf[t];
  if (t == 255) bsum[b] = buf[255];
  if (b == 0 && t == 0) rowptr[0] = 0;
}

__global__ __launch_bounds__(256) void scan_top_kernel(int* __restrict__ bsum, int NB) {
  __shared__ int buf[256];
  int t = threadIdx.x;
  int v = (t < NB) ? bsum[t] : 0;
  buf[t] = v;
  __syncthreads();
  for (int off = 1; off < 256; off <<= 1) {
    int add = (t >= off) ? buf[t - off] : 0;
    __syncthreads();
    buf[t] += add;
    __syncthreads();
  }
  if (t < NB) bsum[t] = buf[t];
}

__global__ __launch_bounds__(256) void scan_add_kernel(int* __restrict__ rowptr,
                                                       const int* __restrict__ bsum, int N) {
  int b = blockIdx.x, t = threadIdx.x, i = b * 256 + t;
  if (b > 0 && i < N) rowptr[i + 1] += bsum[b - 1];
}

__global__ __launch_bounds__(256) void fill_kernel(const int* __restrict__ ei,
                                                   const int* __restrict__ flag,
                                                   int E, int N,
                                                   const int* __restrict__ rowptr,
                                                   int* __restrict__ fillc,
                                                   int* __restrict__ colbuf) {
  int e = blockIdx.x * 256 + threadIdx.x;
  if (e >= E + N) return;
  int s, d;
  if (e < E) { int is32 = *flag; s = load_src(ei, is32, E, e); d = load_dst(ei, is32, E, e); }
  else { s = e - E; d = s; }
  int pos = atomicAdd(&fillc[d], 1);
  colbuf[rowptr[d] + pos] = s;
}

// ---------------------------------------------------------------------------
// prep kernels
// ---------------------------------------------------------------------------
// fp32 x -> fp16 h16 (agg gather buffer)
__global__ __launch_bounds__(256) void split_x16_kernel(const float* __restrict__ h,
                                                        ushort_t* __restrict__ h16,
                                                        int n) {
  int i = (blockIdx.x * 256 + threadIdx.x) * 4;
  if (i >= n) return;
  f32x4v v = *(const f32x4v*)&h[i];
  ushort4v s;
  s[0] = f_to_f16(v[0]); s[1] = f_to_f16(v[1]);
  s[2] = f_to_f16(v[2]); s[3] = f_to_f16(v[3]);
  *(ushort4v*)&h16[i] = s;
}

// All weight prep in one launch: 768 blocks -> Wstack frags (3 layers),
// 64 blocks -> Wp frag.
__global__ __launch_bounds__(256) void prep_weights_kernel(
    const float* __restrict__ W0, const float* __restrict__ W1,
    const float* __restrict__ W2, const float* __restrict__ Wp,
    ushort_t* __restrict__ wsf0, ushort_t* __restrict__ wsf1,
    ushort_t* __restrict__ wsf2, ushort_t* __restrict__ wpf) {
  int b = blockIdx.x;
  if (b < 768) {
    int L = b >> 8;
    const float* W = (L == 0) ? W0 : (L == 1) ? W1 : W2;
    ushort_t* out = (L == 0) ? wsf0 : (L == 1) ? wsf1 : wsf2;
    int t = (b & 255) * 256 + threadIdx.x;   // 0..65535
    int c16 = t >> 13;
    int r = t & 8191;
    int k8 = r >> 7;
    int rem = r & 127;
    int rl = rem >> 3, kl = rem & 7;
    int col = c16 * 16 + rl;
    int k = k8 * 8 + kl;
    int h = k >> 7, f = k & 127;
    out[t] = f_to_f16(0.25f * W[(size_t)f * 512 + h * 128 + col]);
  } else {
    int t = (b - 768) * 256 + threadIdx.x;   // 0..16383
    int blk = t >> 7, rem = t & 127;
    int c16 = blk >> 4, k8 = blk & 15;
    int cl = rem >> 3, kl = rem & 7;
    int col = c16 * 16 + cl, k = k8 * 8 + kl;
    wpf[t] = f_to_f16(Wp[(size_t)k * 128 + col]);
  }
}

// Ws = (1/ln2) * W-folded attention vectors, two layouts.
__global__ __launch_bounds__(256) void wsd_kernel(const float* __restrict__ W,
                                                  const float* __restrict__ a_src,
                                                  const float* __restrict__ a_dst,
                                                  float* __restrict__ Ws4,
                                                  float* __restrict__ Wd4,
                                                  float* __restrict__ Wsh,
                                                  float* __restrict__ Wdh) {
  int wave = threadIdx.x >> 6, lane = threadIdx.x & 63;
  int f = blockIdx.x * 4 + wave;          // grid = 32 -> f in [0,128)
  int base = lane * 8;
  float4 w0 = *(const float4*)&W[(size_t)f * 512 + base];
  float4 w1 = *(const float4*)&W[(size_t)f * 512 + base + 4];
  float4 s0 = *(const float4*)&a_src[base];
  float4 s1 = *(const float4*)&a_src[base + 4];
  float4 d0 = *(const float4*)&a_dst[base];
  float4 d1 = *(const float4*)&a_dst[base + 4];
  float ps = w0.x*s0.x + w0.y*s0.y + w0.z*s0.z + w0.w*s0.w
           + w1.x*s1.x + w1.y*s1.y + w1.z*s1.z + w1.w*s1.w;
  float pd = w0.x*d0.x + w0.y*d0.y + w0.z*d0.z + w0.w*d0.w
           + w1.x*d1.x + w1.y*d1.y + w1.z*d1.z + w1.w*d1.w;
#pragma unroll
  for (int off = 1; off <= 8; off <<= 1) {
    ps += __shfl_xor(ps, off);
    pd += __shfl_xor(pd, off);
  }
  if ((lane & 15) == 0) {
    int h = lane >> 4;
    float vs = ps * INV_LN2, vd = pd * INV_LN2;
    Ws4[f * 4 + h] = vs;
    Wd4[f * 4 + h] = vd;
    Wsh[h * 128 + f] = vs;
    Wdh[h * 128 + f] = vd;
  }
}

// layer-0 al from fp32 x. One wave per node; Ws/Wd in [h][128] layout.
__global__ __launch_bounds__(256) void al_x_kernel(const float* __restrict__ x,
                                                   const float* __restrict__ Wsh,
                                                   const float* __restrict__ Wdh,
                                                   float* __restrict__ al_src,
                                                   float* __restrict__ al_dst, int N) {
  __shared__ float sWs[512], sWd[512];
  int t = threadIdx.x;
  sWs[t] = Wsh[t]; sWs[t + 256] = Wsh[t + 256];
  sWd[t] = Wdh[t]; sWd[t + 256] = Wdh[t + 256];
  __syncthreads();
  int wave = t >> 6, lane = t & 63;
  int n = blockIdx.x * 4 + wave;
  if (n >= N) return;
  float2 hv = *(const float2*)&x[(size_t)n * 128 + lane * 2];
  float p[8];
#pragma unroll
  for (int hh = 0; hh < 4; ++hh) {
    p[hh]     = hv.x * sWs[hh * 128 + 2 * lane] + hv.y * sWs[hh * 128 + 2 * lane + 1];
    p[4 + hh] = hv.x * sWd[hh * 128 + 2 * lane] + hv.y * sWd[hh * 128 + 2 * lane + 1];
  }
#pragma unroll
  for (int off = 32; off; off >>= 1)
#pragma unroll
    for (int i = 0; i < 8; ++i) p[i] += __shfl_xor(p[i], off);
  if (lane == 0) {
#pragma unroll
    for (int hh = 0; hh < 4; ++hh) {
      al_src[n * 4 + hh] = p[hh];
      al_dst[n * 4 + hh] = p[4 + hh];
    }
  }
}

// ---------------------------------------------------------------------------
// aggregation v3 (unchanged): 2 nodes/wave, chunks of 8 edges, quad-specialized
// logits, chunk-granularity rescale, shuffled weight broadcast, fp16 gather.
// ---------------------------------------------------------------------------
__global__ __launch_bounds__(256) void agg_G_kernel(const ushort_t* __restrict__ h16,
                                                    const float* __restrict__ al_src,
                                                    const float* __restrict__ al_dst,
                                                    const int* __restrict__ rowptr,
                                                    const int* __restrict__ colbuf,
                                                    ushort_t* __restrict__ Gf, int N) {
  int wave = threadIdx.x >> 6, lane = threadIdx.x & 63;
  int hl = lane & 31;
  int half_base = lane & 32;
  int q = hl >> 2, hc = hl & 3;
  int qb = lane & ~3;
  int n = blockIdx.x * 8 + wave * 2 + (lane >> 5);
  bool alive = n < N;
  int beg = 0, d = 0;
  float ald_hc = 0.f;
  if (alive) {
    beg = rowptr[n];
    d = rowptr[n + 1] - beg;
    ald_hc = al_dst[(size_t)n * 4 + hc];
  }
  int dm1 = max(d - 1, 0);
  float m_run = -1e30f;
  f32x2 ss01 = {0.f, 0.f}, ss23 = {0.f, 0.f};
  f32x2 a0a = {0.f,0.f}, a0b = {0.f,0.f};
  f32x2 a1a = {0.f,0.f}, a1b = {0.f,0.f};
  f32x2 a2a = {0.f,0.f}, a2b = {0.f,0.f};
  f32x2 a3a = {0.f,0.f}, a3b = {0.f,0.f};

  for (int c0 = 0; c0 < d; c0 += 8) {
    int cn = min(8, d - c0);
    int j = c0 + q;
    int sq = colbuf[beg + min(j, dm1)];
    float e = al_src[(size_t)sq * 4 + hc] + ald_hc;
    e = fmaxf(e, 0.2f * e);
    e = (q < cn) ? e : -1e30f;
    float mc = e;
    mc = fmaxf(mc, __shfl_xor(mc, 4));
    mc = fmaxf(mc, __shfl_xor(mc, 8));
    mc = fmaxf(mc, __shfl_xor(mc, 16));
    float nm = fmaxf(m_run, mc);
    float fown = exp2f(m_run - nm);
    m_run = nm;
    float w_own = (q < cn) ? exp2f(e - nm) : 0.f;
    float f0 = __shfl(fown, qb + 0), f1 = __shfl(fown, qb + 1);
    float f2 = __shfl(fown, qb + 2), f3 = __shfl(fown, qb + 3);
    ss01 *= f32x2{f0, f1}; ss23 *= f32x2{f2, f3};
    f32x2 F0 = {f0, f0}, F1 = {f1, f1}, F2 = {f2, f2}, F3 = {f3, f3};
    a0a *= F0; a0b *= F0; a1a *= F1; a1b *= F1;
    a2a *= F2; a2b *= F2; a3a *= F3; a3b *= F3;
    int s_c = __shfl(sq, half_base);
    ushort4v hv_c = *(const ushort4v*)&h16[(size_t)s_c * 128 + hl * 4];
    for (int jj = 0; jj < cn; ++jj) {
      int s_n = __shfl(sq, half_base + min(jj + 1, cn - 1) * 4);
      ushort4v hv_n = *(const ushort4v*)&h16[(size_t)s_n * 128 + hl * 4];
      int wb = half_base + jj * 4;
      float w0 = __shfl(w_own, wb + 0);
      float w1 = __shfl(w_own, wb + 1);
      float w2 = __shfl(w_own, wb + 2);
      float w3 = __shfl(w_own, wb + 3);
      ss01 += f32x2{w0, w1}; ss23 += f32x2{w2, w3};
      f32x2 v01 = {f16_to_f(hv_c[0]), f16_to_f(hv_c[1])};
      f32x2 v23 = {f16_to_f(hv_c[2]), f16_to_f(hv_c[3])};
      a0a += f32x2{w0, w0} * v01; a0b += f32x2{w0, w0} * v23;
      a1a += f32x2{w1, w1} * v01; a1b += f32x2{w1, w1} * v23;
      a2a += f32x2{w2, w2} * v01; a2b += f32x2{w2, w2} * v23;
      a3a += f32x2{w3, w3} * v01; a3b += f32x2{w3, w3} * v23;
      hv_c = hv_n;
    }
  }
  if (!alive) return;
  float g[4][4];
  float inv;
  inv = 1.f / (ss01.x + 1e-16f);
  g[0][0] = a0a.x * inv; g[0][1] = a0a.y * inv; g[0][2] = a0b.x * inv; g[0][3] = a0b.y * inv;
  inv = 1.f / (ss01.y + 1e-16f);
  g[1][0] = a1a.x * inv; g[1][1] = a1a.y * inv; g[1][2] = a1b.x * inv; g[1][3] = a1b.y * inv;
  inv = 1.f / (ss23.x + 1e-16f);
  g[2][0] = a2a.x * inv; g[2][1] = a2a.y * inv; g[2][2] = a2b.x * inv; g[2][3] = a2b.y * inv;
  inv = 1.f / (ss23.y + 1e-16f);
  g[3][0] = a3a.x * inv; g[3][1] = a3a.y * inv; g[3][2] = a3b.x * inv; g[3][3] = a3b.y * inv;
#pragma unroll
  for (int h = 0; h < 4; ++h) {
    ushort_t q0 = f_to_f16(g[h][0]), q1 = f_to_f16(g[h][1]);
    ushort_t q2 = f_to_f16(g[h][2]), q3 = f_to_f16(g[h][3]);
    size_t o = ((size_t)(n >> 4) * 64 + h * 16 + (hl >> 1)) * 128 + (n & 15) * 8 + (hl & 1) * 4;
    *(uint2*)&Gf[o] = make_uint2((uint_t)q0 | ((uint_t)q1 << 16),
                                 (uint_t)q2 | ((uint_t)q3 << 16));
  }
}

// ---------------------------------------------------------------------------
// Barrier-lean fp16 MFMA GEMM, K-split 2x: each 16-row panel is computed by a
// PAIR of waves (low/high K half), combined via LDS (scalar layout, conflict-
// free) + one barrier. 1-deep A and B register prefetch. 4 waves/block.
// MODE 0: fp16 row out (relu) + fused next-layer al; MODE 1: fp16 frag out
// (relu); MODE 2: fp32 row out (no relu).
// ---------------------------------------------------------------------------
template <int K, int MODE>
__global__ __launch_bounds__(256) void gemm_frag_kernel(
    const ushort_t* __restrict__ Af, const ushort_t* __restrict__ Bf,
    ushort_t* __restrict__ H16, ushort_t* __restrict__ Cf16, float* __restrict__ Cf,
    const float* __restrict__ WsN, const float* __restrict__ WdN,
    float* __restrict__ alS, float* __restrict__ alD,
    int M, const float* __restrict__ bias) {
  constexpr int KT = K >> 5;
  constexpr int KTH = KT >> 1;        // kts per wave (K-split 2x)
  constexpr int PS = 16 * K;          // panel stride (ushorts)
  __shared__ float lacc[2][8][4][64]; // 16 KB, lane-stride 4B: conflict-free
  int lane = threadIdx.x & 63;
  int wv = threadIdx.x >> 6;
  int pair = wv >> 1, khalf = wv & 1;
  int wid = blockIdx.x * 2 + pair;
  int krow = lane >> 4, ml = lane & 15;
  int lb = krow * 128 + ml * 8;
  size_t abase = (size_t)wid * PS + lb + (size_t)khalf * KTH * 512;
  size_t bbase = (size_t)lb + (size_t)khalf * KTH * 512;
  f32x4 acc[8] = {};
  half8 a_c = *(const half8*)&Af[abase];
  half8 b_c[8];
#pragma unroll
  for (int j = 0; j < 8; ++j) b_c[j] = *(const half8*)&Bf[j * PS + bbase];
#pragma unroll
  for (int kt = 0; kt < KTH; ++kt) {
    half8 a_n = a_c;
    half8 b_n[8];
#pragma unroll
    for (int j = 0; j < 8; ++j) b_n[j] = b_c[j];
    if (kt + 1 < KTH) {
      a_n = *(const half8*)&Af[abase + (kt + 1) * 512];
#pragma unroll
      for (int j = 0; j < 8; ++j)
        b_n[j] = *(const half8*)&Bf[j * PS + bbase + (kt + 1) * 512];
    }
#pragma unroll
    for (int j = 0; j < 8; ++j)
      acc[j] = __builtin_amdgcn_mfma_f32_16x16x32_f16(a_c, b_c[j], acc[j], 0, 0, 0);
    a_c = a_n;
#pragma unroll
    for (int j = 0; j < 8; ++j) b_c[j] = b_n[j];
  }
  if (khalf == 1) {
#pragma unroll
    for (int j = 0; j < 8; ++j)
#pragma unroll
      for (int c = 0; c < 4; ++c) lacc[pair][j][c][lane] = acc[j][c];
  }
  __syncthreads();
  if (khalf == 1) return;
#pragma unroll
  for (int j = 0; j < 8; ++j)
#pragma unroll
    for (int c = 0; c < 4; ++c) acc[j][c] += lacc[pair][j][c][lane];

  int wrow0 = wid * 16;
  if (MODE == 0) {
    float ps[4][4] = {};   // [hh][r]
    float pd[4][4] = {};
#pragma unroll
    for (int j = 0; j < 8; ++j) {
      int col = j * 16 + ml;
      float bv = bias[col];
      float4 w4s = *(const float4*)&WsN[col * 4];
      float4 w4d = *(const float4*)&WdN[col * 4];
#pragma unroll
      for (int r = 0; r < 4; ++r) {
        int row = wrow0 + krow * 4 + r;
        float v = fmaxf(acc[j][r] + bv, 0.f);
        if (row < M) H16[(size_t)row * 128 + col] = f_to_f16(v);
        ps[0][r] += v * w4s.x; ps[1][r] += v * w4s.y;
        ps[2][r] += v * w4s.z; ps[3][r] += v * w4s.w;
        pd[0][r] += v * w4d.x; pd[1][r] += v * w4d.y;
        pd[2][r] += v * w4d.z; pd[3][r] += v * w4d.w;
      }
    }
#pragma unroll
    for (int off = 1; off <= 8; off <<= 1) {
#pragma unroll
      for (int hh = 0; hh < 4; ++hh)
#pragma unroll
        for (int r = 0; r < 4; ++r) {
          ps[hh][r] += __shfl_xor(ps[hh][r], off);
          pd[hh][r] += __shfl_xor(pd[hh][r], off);
        }
    }
    if (ml == 0) {
#pragma unroll
      for (int r = 0; r < 4; ++r) {
        int row = wrow0 + krow * 4 + r;
        if (row < M) {
#pragma unroll
          for (int hh = 0; hh < 4; ++hh) {
            alS[row * 4 + hh] = ps[hh][r];
            alD[row * 4 + hh] = pd[hh][r];
          }
        }
      }
    }
  } else {
#pragma unroll
    for (int j = 0; j < 8; ++j) {
      int col = j * 16 + ml;
      float bv = bias[col];
#pragma unroll
      for (int r = 0; r < 4; ++r) {
        int row = wrow0 + krow * 4 + r;
        if (row < M) {
          float v = acc[j][r] + bv;
          if (MODE != 2) v = fmaxf(v, 0.f);
          if (MODE == 1) {
            size_t o = ((size_t)(row >> 4) * 16 + (col >> 3)) * 128 + (row & 15) * 8 + (col & 7);
            Cf16[o] = f_to_f16(v);
          } else {
            Cf[(size_t)row * 128 + col] = v;
          }
        }
      }
    }
  }
}

// ---------------------------------------------------------------------------
extern "C" void kernel_launch(void* const* d_in, const int* in_sizes, int n_in,
                              void* d_out, int out_size, void* d_ws, size_t ws_size,
                              hipStream_t stream) {
  const float* x  = (const float*)d_in[0];
  const int*   ei = (const int*)d_in[1];
  const float* Wl[3]  = {(const float*)d_in[2], (const float*)d_in[6], (const float*)d_in[10]};
  const float* asr[3] = {(const float*)d_in[3], (const float*)d_in[7], (const float*)d_in[11]};
  const float* adr[3] = {(const float*)d_in[4], (const float*)d_in[8], (const float*)d_in[12]};
  const float* bl[3]  = {(const float*)d_in[5], (const float*)d_in[9], (const float*)d_in[13]};
  const float* Wp = (const float*)d_in[14];
  const float* bp = (const float*)d_in[15];

  const int N = in_sizes[0] / 128;   // 50000
  const int E = in_sizes[1] / 2;     // 400000
  const int EN = E + N;
  const int Mtiles = (N + 127) / 128;  // 391
  const int Mp = Mtiles * 128;         // 50048
  const int NB = (N + 255) / 256;
  const int NPB2 = Mp / 16 / 2;        // 1564 GEMM blocks (2 panels x 2 waves)

  char* ws = (char*)d_ws;
  size_t off = 0;
  auto carve = [&](size_t bytes) -> void* {
    void* p = ws + off;
    off = (off + bytes + 255) & ~(size_t)255;
    return p;
  };
  ushort_t* Gf    = (ushort_t*)carve((size_t)Mp * 512 * 2);  // fp16 frag layout
  ushort_t* h16   = (ushort_t*)carve((size_t)N * 128 * 2);   // fp16 h (agg gather)
  ushort_t* h3f   = (ushort_t*)carve((size_t)Mp * 128 * 2);  // fp16 frag (proj input)
  ushort_t* wsf0  = (ushort_t*)carve((size_t)128 * 512 * 2); // fp16 frag Wstack L0
  ushort_t* wsf1  = (ushort_t*)carve((size_t)128 * 512 * 2);
  ushort_t* wsf2  = (ushort_t*)carve((size_t)128 * 512 * 2);
  ushort_t* wpf   = (ushort_t*)carve((size_t)128 * 128 * 2); // fp16 frag Wp
  float*    alsrc = (float*)carve((size_t)N * 4 * 4);
  float*    aldst = (float*)carve((size_t)N * 4 * 4);
  float*    Ws4   = (float*)carve(3 * 512 * 4);
  float*    Wd4   = (float*)carve(3 * 512 * 4);
  float*    Wsh   = (float*)carve(3 * 512 * 4);
  float*    Wdh   = (float*)carve(3 * 512 * 4);
  int*      rowptr= (int*)carve((size_t)(N + 1) * 4);
  int*      deg   = (int*)carve((size_t)N * 4);
  int*      bsum  = (int*)carve(256 * 4);
  int*      fillc = (int*)carve((size_t)N * 4);
  int*      colbuf= (int*)carve((size_t)EN * 4);
  int*      flag  = (int*)carve(256);

  // ---- CSR build ----
  detect_i64_kernel<<<1, 64, 0, stream>>>(ei, flag);
  hipMemsetAsync(deg, 0, (size_t)N * 4, stream);
  hipMemsetAsync(fillc, 0, (size_t)N * 4, stream);
  int ebl = (EN + 255) / 256;
  deg_kernel<<<ebl, 256, 0, stream>>>(ei, flag, E, N, deg);
  scan_blk_kernel<<<NB, 256, 0, stream>>>(deg, rowptr, bsum, N);
  scan_top_kernel<<<1, 256, 0, stream>>>(bsum, NB);
  scan_add_kernel<<<NB, 256, 0, stream>>>(rowptr, bsum, N);
  fill_kernel<<<ebl, 256, 0, stream>>>(ei, flag, E, N, rowptr, fillc, colbuf);

  // ---- x -> fp16; all weight prep upfront ----
  const int n_real = N * 128;
  split_x16_kernel<<<(n_real / 4 + 255) / 256, 256, 0, stream>>>(x, h16, n_real);
  prep_weights_kernel<<<832, 256, 0, stream>>>(Wl[0], Wl[1], Wl[2], Wp,
                                               wsf0, wsf1, wsf2, wpf);
  for (int L = 0; L < 3; ++L)
    wsd_kernel<<<32, 256, 0, stream>>>(Wl[L], asr[L], adr[L],
                                       Ws4 + L * 512, Wd4 + L * 512,
                                       Wsh + L * 512, Wdh + L * 512);
  al_x_kernel<<<(N + 3) / 4, 256, 0, stream>>>(x, Wsh, Wdh, alsrc, aldst, N);

  // ---- 3 GAT layers ----
  ushort_t* wsfL[3] = {wsf0, wsf1, wsf2};
  for (int L = 0; L < 3; ++L) {
    agg_G_kernel<<<Mp / 8, 256, 0, stream>>>(h16, alsrc, aldst,
                                             rowptr, colbuf, Gf, N);
    if (L < 2) {
      gemm_frag_kernel<512, 0><<<NPB2, 256, 0, stream>>>(Gf, wsfL[L],
                                                         h16, nullptr, nullptr,
                                                         Ws4 + (L + 1) * 512, Wd4 + (L + 1) * 512,
                                                         alsrc, aldst, N, bl[L]);
    } else {
      gemm_frag_kernel<512, 1><<<NPB2, 256, 0, stream>>>(Gf, wsfL[L],
                                                         nullptr, h3f, nullptr,
                                                         nullptr, nullptr, nullptr, nullptr,
                                                         N, bl[L]);
    }
  }

  // ---- final projection: out = h3 @ Wp + bp ----
  gemm_frag_kernel<128, 2><<<NPB2, 256, 0, stream>>>(h3f, wpf,
                                                     nullptr, nullptr, (float*)d_out,
                                                     nullptr, nullptr, nullptr, nullptr,
                                                     N, bp);
}